// Round 2
// baseline (8125.031 us; speedup 1.0000x reference)
//
#include <hip/hip_runtime.h>
#include <hip/hip_bf16.h>

#define B_  8
#define N_  512
#define D_  512
#define H_  8
#define DH_ 64
#define DF_ 2048
#define L_  4

// ---------------- f32 copy ----------------
__global__ __launch_bounds__(256) void k_copy(const float* __restrict__ in,
                                              float* __restrict__ out, int n) {
  int i = blockIdx.x * 256 + threadIdx.x;
  if (i < n) out[i] = in[i];
}

// ---------------- C[M,N] = A[M,K] @ W[K,N] + bias[N], opt relu
// 64x64 tile, 16x16 threads, 4x4 per thread, K-tile 16.
__global__ __launch_bounds__(256) void k_gemm_bias(
    const float* __restrict__ A, const float* __restrict__ W,
    const float* __restrict__ bias, float* __restrict__ C,
    int M, int N, int K, int relu)
{
  __shared__ float As[16][68];   // [k][m]
  __shared__ float Bs[16][64];   // [k][n]
  int tx = threadIdx.x, ty = threadIdx.y;
  int tid = ty * 16 + tx;
  int row0 = blockIdx.y * 64;
  int col0 = blockIdx.x * 64;
  float acc[4][4] = {};
  for (int k0 = 0; k0 < K; k0 += 16) {
#pragma unroll
    for (int l = 0; l < 4; ++l) {
      int idx = tid + l * 256;
      int r = idx >> 4, c = idx & 15;       // r: row in tile, c: k
      As[c][r] = A[(long)(row0 + r) * K + k0 + c];
    }
#pragma unroll
    for (int l = 0; l < 4; ++l) {
      int idx = tid + l * 256;
      int r = idx >> 6, c = idx & 63;       // r: k, c: col
      Bs[r][c] = W[(long)(k0 + r) * N + col0 + c];
    }
    __syncthreads();
#pragma unroll
    for (int kk = 0; kk < 16; ++kk) {
      float4 a4 = *(const float4*)&As[kk][ty * 4];
      float4 b4 = *(const float4*)&Bs[kk][tx * 4];
      float av[4] = {a4.x, a4.y, a4.z, a4.w};
      float bv[4] = {b4.x, b4.y, b4.z, b4.w};
#pragma unroll
      for (int i = 0; i < 4; ++i)
#pragma unroll
        for (int j = 0; j < 4; ++j)
          acc[i][j] += av[i] * bv[j];
    }
    __syncthreads();
  }
  float bv[4];
#pragma unroll
  for (int j = 0; j < 4; ++j) bv[j] = bias[col0 + tx * 4 + j];
#pragma unroll
  for (int i = 0; i < 4; ++i) {
    float4 o;
    float* op = (float*)&o;
#pragma unroll
    for (int j = 0; j < 4; ++j) {
      float v = acc[i][j] + bv[j];
      if (relu) v = fmaxf(v, 0.0f);
      op[j] = v;
    }
    *(float4*)&C[(long)(row0 + ty * 4 + i) * N + col0 + tx * 4] = o;
  }
}

// ---------------- S[b,h,i,j] = scale * sum_d Q[b,i,h*64+d] * K[b,j,h*64+d]
// grid: (Nk/64, Nq/64, B*H)
__global__ __launch_bounds__(256) void k_attn_scores(
    const float* __restrict__ Q, const float* __restrict__ K,
    float* __restrict__ S, float scale)
{
  int b = blockIdx.z >> 3, h = blockIdx.z & 7;
  const float* Qb = Q + (long)b * N_ * D_ + h * DH_;
  const float* Kb = K + (long)b * N_ * D_ + h * DH_;
  int i0 = blockIdx.y * 64, j0 = blockIdx.x * 64;
  __shared__ float Qs[64][65];
  __shared__ float Ks[64][65];
  int tx = threadIdx.x, ty = threadIdx.y;
  int tid = ty * 16 + tx;
#pragma unroll
  for (int l = 0; l < 16; ++l) {
    int idx = tid + l * 256;
    int r = idx >> 6, c = idx & 63;
    Qs[r][c] = Qb[(long)(i0 + r) * D_ + c];
    Ks[r][c] = Kb[(long)(j0 + r) * D_ + c];
  }
  __syncthreads();
  float acc[4][4] = {};
#pragma unroll 8
  for (int d = 0; d < 64; ++d) {
    float qv[4], kv[4];
#pragma unroll
    for (int u = 0; u < 4; ++u) { qv[u] = Qs[ty * 4 + u][d]; kv[u] = Ks[tx * 4 + u][d]; }
#pragma unroll
    for (int i = 0; i < 4; ++i)
#pragma unroll
      for (int j = 0; j < 4; ++j)
        acc[i][j] += qv[i] * kv[j];
  }
  float* Sb = S + (long)blockIdx.z * N_ * N_;
#pragma unroll
  for (int i = 0; i < 4; ++i) {
    float4 o;
    float* op = (float*)&o;
#pragma unroll
    for (int j = 0; j < 4; ++j) op[j] = acc[i][j] * scale;
    *(float4*)&Sb[(long)(i0 + ty * 4 + i) * N_ + j0 + tx * 4] = o;
  }
}

// ---------------- masked softmax over last dim (512), one block per row
// rows = B*H*Nq; key-pad mask kvm[b*N_+j]==0 -> -1e9
__global__ __launch_bounds__(256) void k_attn_softmax(
    float* __restrict__ S, const int* __restrict__ kvm)
{
  long row = blockIdx.x;
  int b = (int)(row >> 12);          // row / (H*Nq) = / 4096
  float* p = S + row * N_;
  int t = threadIdx.x;
  const int* mb = kvm + b * N_;
  float v0 = mb[t]       ? p[t]       : -1e9f;
  float v1 = mb[t + 256] ? p[t + 256] : -1e9f;
  float m = fmaxf(v0, v1);
#pragma unroll
  for (int o = 32; o > 0; o >>= 1) m = fmaxf(m, __shfl_down(m, o, 64));
  __shared__ float rmax[4];
  __shared__ float rsum[4];
  int lane = t & 63, wid = t >> 6;
  if (lane == 0) rmax[wid] = m;
  __syncthreads();
  m = fmaxf(fmaxf(rmax[0], rmax[1]), fmaxf(rmax[2], rmax[3]));
  float e0 = __expf(v0 - m), e1 = __expf(v1 - m);
  float s = e0 + e1;
#pragma unroll
  for (int o = 32; o > 0; o >>= 1) s += __shfl_down(s, o, 64);
  if (lane == 0) rsum[wid] = s;
  __syncthreads();
  s = rsum[0] + rsum[1] + rsum[2] + rsum[3];
  float inv = 1.0f / s;
  p[t] = e0 * inv;
  p[t + 256] = e1 * inv;
}

// ---------------- batched C = P @ X  (both f32)
__global__ __launch_bounds__(256) void k_batched_pm(
    const float* __restrict__ P, const float* __restrict__ X, float* __restrict__ C,
    int Mx, int Nx, int Kx, int Hh,
    long pBatch, long xBatch, int xHead, int xStride,
    long cBatch, int cHead, int cStride)
{
  int bz = blockIdx.z;
  int b = bz / Hh;
  int h = bz - b * Hh;
  const float* Pb = P + (long)bz * pBatch;
  const float* Xb = X + (long)b * xBatch + h * xHead;
  float* Cb = C + (long)b * cBatch + h * cHead;
  int i0 = blockIdx.y * 64, n0 = blockIdx.x * 64;
  __shared__ float Ps[64][65];
  __shared__ float Xs[64][65];
  int tx = threadIdx.x, ty = threadIdx.y;
  int tid = ty * 16 + tx;
  float acc[4][4] = {};
  for (int k0 = 0; k0 < Kx; k0 += 64) {
#pragma unroll
    for (int l = 0; l < 16; ++l) {
      int idx = tid + l * 256;
      int r = idx >> 6, c = idx & 63;
      Ps[r][c] = Pb[(long)(i0 + r) * Kx + k0 + c];
      Xs[r][c] = Xb[(long)(k0 + r) * xStride + n0 + c];
    }
    __syncthreads();
#pragma unroll 8
    for (int kk = 0; kk < 64; ++kk) {
      float pv[4], xv[4];
#pragma unroll
      for (int u = 0; u < 4; ++u) { pv[u] = Ps[ty * 4 + u][kk]; xv[u] = Xs[kk][tx * 4 + u]; }
#pragma unroll
      for (int i = 0; i < 4; ++i)
#pragma unroll
        for (int j = 0; j < 4; ++j)
          acc[i][j] += pv[i] * xv[j];
    }
    __syncthreads();
  }
#pragma unroll
  for (int i = 0; i < 4; ++i)
#pragma unroll
    for (int j = 0; j < 4; ++j)
      Cb[(long)(i0 + ty * 4 + i) * cStride + n0 + tx * 4 + j] = acc[i][j];
}

// ---------------- y = LN(x + r) * g + b, one block per row of 512
__global__ __launch_bounds__(256) void k_ln_res(
    const float* __restrict__ x, const float* __restrict__ r,
    const float* __restrict__ g, const float* __restrict__ bta,
    float* __restrict__ y)
{
  long row = blockIdx.x;
  int t = threadIdx.x;
  const float* xr = x + row * D_;
  const float* rr = r + row * D_;
  float v0 = xr[t] + rr[t];
  float v1 = xr[t + 256] + rr[t + 256];
  float s = v0 + v1;
  float ss = v0 * v0 + v1 * v1;
#pragma unroll
  for (int o = 32; o > 0; o >>= 1) {
    s += __shfl_down(s, o, 64);
    ss += __shfl_down(ss, o, 64);
  }
  __shared__ float rs[4];
  __shared__ float rss[4];
  int lane = t & 63, wid = t >> 6;
  if (lane == 0) { rs[wid] = s; rss[wid] = ss; }
  __syncthreads();
  s = rs[0] + rs[1] + rs[2] + rs[3];
  ss = rss[0] + rss[1] + rss[2] + rss[3];
  float mean = s * (1.0f / D_);
  float var = ss * (1.0f / D_) - mean * mean;
  float rstd = rsqrtf(var + 1e-5f);
  float* yr = y + row * D_;
  yr[t]       = (v0 - mean) * rstd * g[t]       + bta[t];
  yr[t + 256] = (v1 - mean) * rstd * g[t + 256] + bta[t + 256];
}

// ---------------- s[b,i,j] = sum_k V[b,i,k]*w[k]*Q[b,j,k] + att_b
__global__ __launch_bounds__(256) void k_final_scores(
    const float* __restrict__ V, const float* __restrict__ Q,
    const float* __restrict__ w, const float* __restrict__ ab,
    float* __restrict__ S)
{
  int b = blockIdx.z;
  int i0 = blockIdx.y * 64, j0 = blockIdx.x * 64;
  const float* Vb = V + (long)b * N_ * D_;
  const float* Qb = Q + (long)b * N_ * D_;
  __shared__ float Vs[64][65];
  __shared__ float Qs[64][65];
  int tx = threadIdx.x, ty = threadIdx.y;
  int tid = ty * 16 + tx;
  float acc[4][4] = {};
  for (int k0 = 0; k0 < D_; k0 += 64) {
#pragma unroll
    for (int l = 0; l < 16; ++l) {
      int idx = tid + l * 256;
      int r = idx >> 6, c = idx & 63;
      Vs[r][c] = Vb[(long)(i0 + r) * D_ + k0 + c] * w[k0 + c];
      Qs[r][c] = Qb[(long)(j0 + r) * D_ + k0 + c];
    }
    __syncthreads();
#pragma unroll 8
    for (int kk = 0; kk < 64; ++kk) {
      float vv[4], qv[4];
#pragma unroll
      for (int u = 0; u < 4; ++u) { vv[u] = Vs[ty * 4 + u][kk]; qv[u] = Qs[tx * 4 + u][kk]; }
#pragma unroll
      for (int i = 0; i < 4; ++i)
#pragma unroll
        for (int j = 0; j < 4; ++j)
          acc[i][j] += vv[i] * qv[j];
    }
    __syncthreads();
  }
  float bias = ab[0];
  float* Sb = S + (long)b * N_ * N_;
#pragma unroll
  for (int i = 0; i < 4; ++i)
#pragma unroll
    for (int j = 0; j < 4; ++j)
      Sb[(long)(i0 + ty * 4 + i) * N_ + j0 + tx * 4 + j] = acc[i][j] + bias;
}

// ---------------- cross-masked softmax: rows = B*NV, mask = v_pad[i] | q_pad[j]
__global__ __launch_bounds__(256) void k_softmax_cross(
    float* __restrict__ S, const int* __restrict__ vm, const int* __restrict__ qm)
{
  long row = blockIdx.x;
  int b = (int)(row >> 9);
  int i = (int)(row & 511);
  bool rowpad = (vm[b * N_ + i] == 0);
  float* p = S + row * N_;
  const int* qb = qm + b * N_;
  int t = threadIdx.x;
  float v0 = (rowpad || qb[t] == 0)       ? -1e9f : p[t];
  float v1 = (rowpad || qb[t + 256] == 0) ? -1e9f : p[t + 256];
  float m = fmaxf(v0, v1);
#pragma unroll
  for (int o = 32; o > 0; o >>= 1) m = fmaxf(m, __shfl_down(m, o, 64));
  __shared__ float rmax[4];
  __shared__ float rsum[4];
  int lane = t & 63, wid = t >> 6;
  if (lane == 0) rmax[wid] = m;
  __syncthreads();
  m = fmaxf(fmaxf(rmax[0], rmax[1]), fmaxf(rmax[2], rmax[3]));
  float e0 = __expf(v0 - m), e1 = __expf(v1 - m);
  float s = e0 + e1;
#pragma unroll
  for (int o = 32; o > 0; o >>= 1) s += __shfl_down(s, o, 64);
  if (lane == 0) rsum[wid] = s;
  __syncthreads();
  s = rsum[0] + rsum[1] + rsum[2] + rsum[3];
  float inv = 1.0f / s;
  p[t] = e0 * inv;
  p[t + 256] = e1 * inv;
}

// ---------------- out[b,k] = (1/512) * sum_i V[b,i,k] * QT[b,i,k]
__global__ __launch_bounds__(256) void k_final_out(
    const float* __restrict__ V, const float* __restrict__ QT, float* __restrict__ out)
{
  int b = blockIdx.x >> 1;
  int k = ((blockIdx.x & 1) << 8) + threadIdx.x;
  const float* Vb = V + (long)b * N_ * D_ + k;
  const float* Tb = QT + (long)b * N_ * D_ + k;
  float acc = 0.0f;
  for (int i = 0; i < N_; ++i) acc += Vb[(long)i * D_] * Tb[(long)i * D_];
  out[b * D_ + k] = acc * (1.0f / 512.0f);
}

extern "C" void kernel_launch(void* const* d_in, const int* in_sizes, int n_in,
                              void* d_out, int out_size, void* d_ws, size_t ws_size,
                              hipStream_t stream)
{
  const float* in_v   = (const float*)d_in[0];
  const float* in_q   = (const float*)d_in[1];
  const int*   v_mask = (const int*)  d_in[2];
  const int*   q_mask = (const int*)  d_in[3];
  const float* aw  = (const float*)d_in[4];
  const float* ab  = (const float*)d_in[5];
  const float* awo = (const float*)d_in[6];
  const float* abo = (const float*)d_in[7];
  const float* lg  = (const float*)d_in[8];
  const float* lb  = (const float*)d_in[9];
  const float* fw1 = (const float*)d_in[10];
  const float* fb1 = (const float*)d_in[11];
  const float* fw2 = (const float*)d_in[12];
  const float* fb2 = (const float*)d_in[13];
  const float* atw = (const float*)d_in[14];
  const float* atb = (const float*)d_in[15];
  float* out = (float*)d_out;

  const long SZ = (long)B_ * N_ * D_;   // 2,097,152 floats
  float* ws  = (float*)d_ws;
  float* Vcur = ws;
  float* Qcur = ws + 1 * SZ;
  float* VA   = ws + 2 * SZ;
  float* QA   = ws + 3 * SZ;
  float* VQ   = ws + 4 * SZ;
  float* T    = ws + 5 * SZ;
  float* Qp   = ws + 6 * SZ;
  float* Kp   = ws + 7 * SZ;
  float* Vp   = ws + 8 * SZ;
  float* Ob   = ws + 9 * SZ;
  float* Sb   = ws + 10 * SZ;  // 8*SZ floats (B*H*N*N); also FFN hidden (4*SZ)

  dim3 blk(16, 16);
  dim3 gProj(8, 64);       // N=512
  dim3 gFc1(32, 64);       // N=2048
  dim3 gScore(8, 8, 64);
  dim3 gAV(1, 8, 64);

  k_copy<<<(int)((SZ + 255) / 256), 256, 0, stream>>>(in_v, Vcur, (int)SZ);
  k_copy<<<(int)((SZ + 255) / 256), 256, 0, stream>>>(in_q, Qcur, (int)SZ);

  auto mha = [&](const float* xq, const float* xkv, const int* kvm, int mi, float* target) {
    const float* w  = aw  + (long)mi * 3 * D_ * D_;
    const float* bb = ab  + (long)mi * 3 * D_;
    const float* wo = awo + (long)mi * D_ * D_;
    const float* bo = abo + (long)mi * D_;
    k_gemm_bias<<<gProj, blk, 0, stream>>>(xq,  w,                bb,          Qp, 4096, 512, 512, 0);
    k_gemm_bias<<<gProj, blk, 0, stream>>>(xkv, w + D_ * D_,      bb + D_,     Kp, 4096, 512, 512, 0);
    k_gemm_bias<<<gProj, blk, 0, stream>>>(xkv, w + 2 * D_ * D_,  bb + 2 * D_, Vp, 4096, 512, 512, 0);
    k_attn_scores<<<gScore, blk, 0, stream>>>(Qp, Kp, Sb, 0.125f);
    k_attn_softmax<<<B_ * H_ * N_, 256, 0, stream>>>(Sb, kvm);
    k_batched_pm<<<gAV, blk, 0, stream>>>(Sb, Vp, Ob, 512, 64, 512, H_,
                                          (long)N_ * N_, (long)N_ * D_, DH_, D_,
                                          (long)N_ * D_, DH_, D_);
    k_gemm_bias<<<gProj, blk, 0, stream>>>(Ob, wo, bo, target, 4096, 512, 512, 0);
  };

  for (int l = 0; l < L_; ++l) {
    const float* lgl = lg + (long)l * 6 * D_;
    const float* lbl = lb + (long)l * 6 * D_;
    // self-attn v -> VA
    mha(Vcur, Vcur, v_mask, l * 4 + 0, T);
    k_ln_res<<<4096, 256, 0, stream>>>(Vcur, T, lgl + 0 * D_, lbl + 0 * D_, VA);
    // self-attn q -> QA
    mha(Qcur, Qcur, q_mask, l * 4 + 1, T);
    k_ln_res<<<4096, 256, 0, stream>>>(Qcur, T, lgl + 1 * D_, lbl + 1 * D_, QA);
    // cross: vq consumes (VA, QA); qv consumes (QA, VQ_out)
    mha(VA, QA, q_mask, l * 4 + 2, VQ);
    mha(QA, VQ, v_mask, l * 4 + 3, T);
    k_ln_res<<<4096, 256, 0, stream>>>(Vcur, VQ, lgl + 2 * D_, lbl + 2 * D_, Vcur);
    k_ln_res<<<4096, 256, 0, stream>>>(Qcur, T, lgl + 3 * D_, lbl + 3 * D_, Qcur);
    // FFN v (hidden lives in Sb region)
    k_gemm_bias<<<gFc1, blk, 0, stream>>>(Vcur, fw1 + (long)(l * 2 + 0) * D_ * DF_,
                                          fb1 + (long)(l * 2 + 0) * DF_, Sb, 4096, 2048, 512, 1);
    k_gemm_bias<<<gProj, blk, 0, stream>>>(Sb, fw2 + (long)(l * 2 + 0) * DF_ * D_,
                                           fb2 + (long)(l * 2 + 0) * D_, T, 4096, 512, 2048, 0);
    k_ln_res<<<4096, 256, 0, stream>>>(Vcur, T, lgl + 4 * D_, lbl + 4 * D_, Vcur);
    // FFN q
    k_gemm_bias<<<gFc1, blk, 0, stream>>>(Qcur, fw1 + (long)(l * 2 + 1) * D_ * DF_,
                                          fb1 + (long)(l * 2 + 1) * DF_, Sb, 4096, 2048, 512, 1);
    k_gemm_bias<<<gProj, blk, 0, stream>>>(Sb, fw2 + (long)(l * 2 + 1) * DF_ * D_,
                                           fb2 + (long)(l * 2 + 1) * D_, T, 4096, 512, 2048, 0);
    k_ln_res<<<4096, 256, 0, stream>>>(Qcur, T, lgl + 5 * D_, lbl + 5 * D_, Qcur);
  }

  // final bilinear attention pooling
  k_final_scores<<<dim3(8, 8, 8), blk, 0, stream>>>(Vcur, Qcur, atw, atb, Sb);
  k_softmax_cross<<<B_ * N_, 256, 0, stream>>>(Sb, v_mask, q_mask);
  k_batched_pm<<<dim3(8, 8, 8), blk, 0, stream>>>(Sb, Qcur, T, 512, 512, 512, 1,
                                                  (long)N_ * N_, (long)N_ * D_, 0, D_,
                                                  (long)N_ * D_, 0, D_);
  k_final_out<<<16, 256, 0, stream>>>(Vcur, T, out);

  (void)in_sizes; (void)n_in; (void)out_size; (void)ws_size;
}

// Round 3
// 2895.373 us; speedup vs baseline: 2.8062x; 2.8062x over previous
//
#include <hip/hip_runtime.h>
#include <hip/hip_bf16.h>

typedef __hip_bfloat16 bf16;
typedef __attribute__((ext_vector_type(8))) short short8;
typedef __attribute__((ext_vector_type(4))) float f32x4;

#define AS1 __attribute__((address_space(1)))
#define AS3 __attribute__((address_space(3)))

#define B_  8
#define N_  512
#define D_  512
#define H_  8
#define DH_ 64
#define DF_ 2048
#define L_  4

// ---------------- input prep: fp32 copy + bf16 shadow ----------------
__global__ __launch_bounds__(256) void k_prep(const float* __restrict__ in,
                                              float* __restrict__ f,
                                              bf16* __restrict__ b, int n) {
  int i = blockIdx.x * 256 + threadIdx.x;
  if (i < n) { float v = in[i]; f[i] = v; b[i] = __float2bfloat16(v); }
}

// ---------------- per-layer weight transpose + cast: W[K,N] f32 -> Wt[N,K] bf16
// 8192 blocks of 256 threads, 32x32 tiles. Layout in WT (bf16 elems):
//   id 0..15 (mha m=id>>2, part=id&3: q,k,v,wo): 512x512 at id*262144
//   id 16,17 (fc1): [2048][512] at 4194304 + (id-16)*1048576
//   id 18,19 (fc2): [512][2048] at 6291456 + (id-18)*1048576
__global__ __launch_bounds__(256) void k_wt(const float* __restrict__ aw_l,
                                            const float* __restrict__ awo_l,
                                            const float* __restrict__ fw1_l,
                                            const float* __restrict__ fw2_l,
                                            bf16* __restrict__ WT)
{
  __shared__ float Ls[32][33];
  int bx = blockIdx.x;
  const float* src; bf16* dst; int R, C, tr, tc;
  if (bx < 4096) {
    int id = bx >> 8, t = bx & 255;
    int m = id >> 2, part = id & 3;
    src = (part < 3) ? (aw_l + ((long)m * 3 + part) * D_ * D_)
                     : (awo_l + (long)m * D_ * D_);
    dst = WT + (long)id * 262144; R = 512; C = 512; tr = t >> 4; tc = t & 15;
  } else if (bx < 6144) {
    int q = bx - 4096; int id = q >> 10; int t = q & 1023;
    src = fw1_l + (long)id * D_ * DF_; dst = WT + 4194304 + (long)id * 1048576;
    R = 512; C = 2048; tr = t >> 6; tc = t & 63;
  } else {
    int q = bx - 6144; int id = q >> 10; int t = q & 1023;
    src = fw2_l + (long)id * DF_ * D_; dst = WT + 6291456 + (long)id * 1048576;
    R = 2048; C = 512; tr = t >> 4; tc = t & 15;
  }
  int tt = threadIdx.x;
#pragma unroll
  for (int p = 0; p < 4; ++p) {
    int idx = tt + p * 256; int lr = idx >> 5, lc = idx & 31;
    Ls[lr][lc] = src[(long)(tr * 32 + lr) * C + tc * 32 + lc];
  }
  __syncthreads();
#pragma unroll
  for (int p = 0; p < 4; ++p) {
    int idx = tt + p * 256; int lr = idx >> 5, lc = idx & 31;
    dst[(long)(tc * 32 + lr) * R + tr * 32 + lc] = __float2bfloat16(Ls[lc][lr]);
  }
}

// ---------------- MFMA GEMM (m97 structure): C = A @ B^T (+bias)*... both operands
// [rows][K-contiguous] bf16. 128 x BN tile, BK=32, 4 waves, 16x16x32 bf16 MFMA.
// Batched via blockIdx.z -> (zb=z/Hh, zh=z%Hh) with per-b / per-h strides.
// vt: V-projection transposed store into Vp_t[b][h][d][token].
template<int BN>
__global__ __launch_bounds__(256, 2) void k_mfma(
    const bf16* __restrict__ A, long aB, long aH, int lda,
    const bf16* __restrict__ Bm, long bB, long bH, int ldb,
    const float* __restrict__ bias, float scale, int relu,
    float* __restrict__ Cf, long cfB, long cfH, int ldcf,
    bf16* __restrict__ Cb, long cbB, long cbH, int ldcb,
    int K, int Hh, int vt)
{
  constexpr int MI = (BN == 128) ? 4 : 2;
  constexpr int NI = 4;
  __shared__ short As[128 * 32];
  __shared__ short Bs[BN * 32];
  int tid = threadIdx.x;
  int w = tid >> 6, lane = tid & 63;
  int z = blockIdx.z;
  int zb = z / Hh, zh = z - zb * Hh;
  const bf16* Ab = A + zb * aB + zh * aH;
  const bf16* Bb = Bm + zb * bB + zh * bH;
  int row0 = blockIdx.y * 128;
  int col0 = blockIdx.x * BN;
  int rw = (BN == 128) ? ((w >> 1) * 64) : (w * 32);
  int cw = (BN == 128) ? ((w & 1) * 64) : 0;
  int quad = lane >> 4, l16 = lane & 15;

  f32x4 acc[MI][NI];
#pragma unroll
  for (int i = 0; i < MI; ++i)
#pragma unroll
    for (int j = 0; j < NI; ++j) acc[i][j] = {0.f, 0.f, 0.f, 0.f};

  for (int k0 = 0; k0 < K; k0 += 32) {
    // stage A tile (128 rows x 32 k = 8 KB), LDS row-major [m][32]
#pragma unroll
    for (int i = 0; i < 2; ++i) {
      int o = i * 4096 + w * 1024 + lane * 16;
      int r = o >> 6;
      const bf16* g = Ab + (long)(row0 + r) * lda + k0 + ((o & 63) >> 1);
      char* lp = (char*)As + i * 4096 + w * 1024;
      __builtin_amdgcn_global_load_lds((const AS1 void*)g, (AS3 void*)lp, 16, 0, 0);
    }
    // stage B tile (BN rows x 32 k)
    constexpr int BI = (BN == 128) ? 2 : 1;
#pragma unroll
    for (int i = 0; i < BI; ++i) {
      int o = i * 4096 + w * 1024 + lane * 16;
      int r = o >> 6;
      const bf16* g = Bb + (long)(col0 + r) * ldb + k0 + ((o & 63) >> 1);
      char* lp = (char*)Bs + i * 4096 + w * 1024;
      __builtin_amdgcn_global_load_lds((const AS1 void*)g, (AS3 void*)lp, 16, 0, 0);
    }
    __syncthreads();
    short8 af[MI], bfr[NI];
#pragma unroll
    for (int mi = 0; mi < MI; ++mi)
      af[mi] = *(const short8*)&As[(rw + mi * 16 + l16) * 32 + quad * 8];
#pragma unroll
    for (int ni = 0; ni < NI; ++ni)
      bfr[ni] = *(const short8*)&Bs[(cw + ni * 16 + l16) * 32 + quad * 8];
#pragma unroll
    for (int mi = 0; mi < MI; ++mi)
#pragma unroll
      for (int ni = 0; ni < NI; ++ni)
        acc[mi][ni] = __builtin_amdgcn_mfma_f32_16x16x32_bf16(af[mi], bfr[ni], acc[mi][ni], 0, 0, 0);
    __syncthreads();
  }

#pragma unroll
  for (int mi = 0; mi < MI; ++mi)
#pragma unroll
    for (int ni = 0; ni < NI; ++ni) {
      int cg = col0 + cw + ni * 16 + l16;
      float bv = bias ? bias[cg] : 0.0f;
#pragma unroll
      for (int r = 0; r < 4; ++r) {
        int rg = row0 + rw + mi * 16 + quad * 4 + r;
        float v = acc[mi][ni][r] * scale + bv;
        if (relu) v = fmaxf(v, 0.0f);
        if (vt) {
          int tb = rg >> 9, ti = rg & 511, th = cg >> 6, td = cg & 63;
          Cb[((long)((tb * 8 + th) * 64 + td) << 9) + ti] = __float2bfloat16(v);
        } else {
          if (Cf) Cf[zb * cfB + zh * cfH + (long)rg * ldcf + cg] = v;
          if (Cb) Cb[zb * cbB + zh * cbH + (long)rg * ldcb + cg] = __float2bfloat16(v);
        }
      }
    }
}

// ---------------- masked softmax over 512, fp32 scores in, bf16 probs written
// in-place into the FIRST 1 KB of each row's own 2 KB (no cross-block overlap).
__global__ __launch_bounds__(256) void k_softmax_p(float* __restrict__ S,
                                                   const int* __restrict__ kvm)
{
  long row = blockIdx.x;
  int b = (int)(row >> 12);          // rows per batch = H*N = 4096
  float* p = S + row * N_;
  bf16* pb = (bf16*)p;
  int t = threadIdx.x;
  const int* mb = kvm + b * N_;
  float v0 = mb[t]       ? p[t]       : -1e9f;
  float v1 = mb[t + 256] ? p[t + 256] : -1e9f;
  float m = fmaxf(v0, v1);
#pragma unroll
  for (int o = 32; o > 0; o >>= 1) m = fmaxf(m, __shfl_down(m, o, 64));
  __shared__ float rmax[4];
  __shared__ float rsum[4];
  int lane = t & 63, wid = t >> 6;
  if (lane == 0) rmax[wid] = m;
  __syncthreads();
  m = fmaxf(fmaxf(rmax[0], rmax[1]), fmaxf(rmax[2], rmax[3]));
  float e0 = __expf(v0 - m), e1 = __expf(v1 - m);
  float s = e0 + e1;
#pragma unroll
  for (int o = 32; o > 0; o >>= 1) s += __shfl_down(s, o, 64);
  if (lane == 0) rsum[wid] = s;
  __syncthreads();   // also guarantees all fp32 reads complete before bf16 writes
  s = rsum[0] + rsum[1] + rsum[2] + rsum[3];
  float inv = 1.0f / s;
  pb[t]       = __float2bfloat16(e0 * inv);
  pb[t + 256] = __float2bfloat16(e1 * inv);
}

// ---------------- y = LN(x + r) * g + b; fp32 and/or bf16 outputs ----------------
__global__ __launch_bounds__(256) void k_ln_res(
    const float* __restrict__ x, const float* __restrict__ r,
    const float* __restrict__ g, const float* __restrict__ bta,
    float* __restrict__ yf, bf16* __restrict__ yb)
{
  long row = blockIdx.x;
  int t = threadIdx.x;
  const float* xr = x + row * D_;
  const float* rr = r + row * D_;
  float v0 = xr[t] + rr[t];
  float v1 = xr[t + 256] + rr[t + 256];
  float s = v0 + v1;
  float ss = v0 * v0 + v1 * v1;
#pragma unroll
  for (int o = 32; o > 0; o >>= 1) {
    s += __shfl_down(s, o, 64);
    ss += __shfl_down(ss, o, 64);
  }
  __shared__ float rs[4];
  __shared__ float rss[4];
  int lane = t & 63, wid = t >> 6;
  if (lane == 0) { rs[wid] = s; rss[wid] = ss; }
  __syncthreads();
  s = rs[0] + rs[1] + rs[2] + rs[3];
  ss = rss[0] + rss[1] + rss[2] + rss[3];
  float mean = s * (1.0f / D_);
  float var = ss * (1.0f / D_) - mean * mean;
  float rstd = rsqrtf(var + 1e-5f);
  float o0 = (v0 - mean) * rstd * g[t]       + bta[t];
  float o1 = (v1 - mean) * rstd * g[t + 256] + bta[t + 256];
  if (yf) { float* yr = yf + row * D_; yr[t] = o0; yr[t + 256] = o1; }
  if (yb) { bf16* yr = yb + row * D_; yr[t] = __float2bfloat16(o0); yr[t + 256] = __float2bfloat16(o1); }
}

// ---------------- final: s[b,i,j] = sum_k V[b,i,k]*w[k]*Q[b,j,k] + att_b (fp32)
__global__ __launch_bounds__(256) void k_final_scores(
    const float* __restrict__ V, const float* __restrict__ Q,
    const float* __restrict__ w, const float* __restrict__ ab,
    float* __restrict__ S)
{
  int b = blockIdx.z;
  int i0 = blockIdx.y * 64, j0 = blockIdx.x * 64;
  const float* Vb = V + (long)b * N_ * D_;
  const float* Qb = Q + (long)b * N_ * D_;
  __shared__ float Vs[64][65];
  __shared__ float Qs[64][65];
  int tx = threadIdx.x, ty = threadIdx.y;
  int tid = ty * 16 + tx;
  float acc[4][4] = {};
  for (int k0 = 0; k0 < D_; k0 += 64) {
#pragma unroll
    for (int l = 0; l < 16; ++l) {
      int idx = tid + l * 256;
      int r = idx >> 6, c = idx & 63;
      Vs[r][c] = Vb[(long)(i0 + r) * D_ + k0 + c] * w[k0 + c];
      Qs[r][c] = Qb[(long)(j0 + r) * D_ + k0 + c];
    }
    __syncthreads();
#pragma unroll 8
    for (int kk = 0; kk < 64; ++kk) {
      float vv[4], qv[4];
#pragma unroll
      for (int u = 0; u < 4; ++u) { vv[u] = Vs[ty * 4 + u][kk]; qv[u] = Qs[tx * 4 + u][kk]; }
#pragma unroll
      for (int i = 0; i < 4; ++i)
#pragma unroll
        for (int j = 0; j < 4; ++j)
          acc[i][j] += vv[i] * qv[j];
    }
    __syncthreads();
  }
  float bias = ab[0];
  float* Sb = S + (long)b * N_ * N_;
#pragma unroll
  for (int i = 0; i < 4; ++i)
#pragma unroll
    for (int j = 0; j < 4; ++j)
      Sb[(long)(i0 + ty * 4 + i) * N_ + j0 + tx * 4 + j] = acc[i][j] + bias;
}

// ---------------- final cross-masked softmax (fp32 in place) ----------------
__global__ __launch_bounds__(256) void k_softmax_cross(
    float* __restrict__ S, const int* __restrict__ vm, const int* __restrict__ qm)
{
  long row = blockIdx.x;
  int b = (int)(row >> 9);
  int i = (int)(row & 511);
  bool rowpad = (vm[b * N_ + i] == 0);
  float* p = S + row * N_;
  const int* qb = qm + b * N_;
  int t = threadIdx.x;
  float v0 = (rowpad || qb[t] == 0)       ? -1e9f : p[t];
  float v1 = (rowpad || qb[t + 256] == 0) ? -1e9f : p[t + 256];
  float m = fmaxf(v0, v1);
#pragma unroll
  for (int o = 32; o > 0; o >>= 1) m = fmaxf(m, __shfl_down(m, o, 64));
  __shared__ float rmax[4];
  __shared__ float rsum[4];
  int lane = t & 63, wid = t >> 6;
  if (lane == 0) rmax[wid] = m;
  __syncthreads();
  m = fmaxf(fmaxf(rmax[0], rmax[1]), fmaxf(rmax[2], rmax[3]));
  float e0 = __expf(v0 - m), e1 = __expf(v1 - m);
  float s = e0 + e1;
#pragma unroll
  for (int o = 32; o > 0; o >>= 1) s += __shfl_down(s, o, 64);
  if (lane == 0) rsum[wid] = s;
  __syncthreads();
  s = rsum[0] + rsum[1] + rsum[2] + rsum[3];
  float inv = 1.0f / s;
  p[t] = e0 * inv;
  p[t + 256] = e1 * inv;
}

// ---------------- final: T[b] = A[b](512x512) @ Q[b](512x512), fp32 ----------------
__global__ __launch_bounds__(256) void k_final_pm(
    const float* __restrict__ P, const float* __restrict__ X, float* __restrict__ C)
{
  int b = blockIdx.z;
  const float* Pb = P + (long)b * N_ * N_;
  const float* Xb = X + (long)b * N_ * D_;
  float* Cb2 = C + (long)b * N_ * D_;
  int i0 = blockIdx.y * 64, n0 = blockIdx.x * 64;
  __shared__ float Ps[64][65];
  __shared__ float Xs[64][65];
  int tx = threadIdx.x, ty = threadIdx.y;
  int tid = ty * 16 + tx;
  float acc[4][4] = {};
  for (int k0 = 0; k0 < N_; k0 += 64) {
#pragma unroll
    for (int l = 0; l < 16; ++l) {
      int idx = tid + l * 256;
      int r = idx >> 6, c = idx & 63;
      Ps[r][c] = Pb[(long)(i0 + r) * N_ + k0 + c];
      Xs[r][c] = Xb[(long)(k0 + r) * D_ + n0 + c];
    }
    __syncthreads();
#pragma unroll 8
    for (int kk = 0; kk < 64; ++kk) {
      float pv[4], xv[4];
#pragma unroll
      for (int u = 0; u < 4; ++u) { pv[u] = Ps[ty * 4 + u][kk]; xv[u] = Xs[kk][tx * 4 + u]; }
#pragma unroll
      for (int i = 0; i < 4; ++i)
#pragma unroll
        for (int j = 0; j < 4; ++j)
          acc[i][j] += pv[i] * xv[j];
    }
    __syncthreads();
  }
#pragma unroll
  for (int i = 0; i < 4; ++i)
#pragma unroll
    for (int j = 0; j < 4; ++j)
      Cb2[(long)(i0 + ty * 4 + i) * D_ + n0 + tx * 4 + j] = acc[i][j];
}

// ---------------- out[b,k] = (1/512) * sum_i V[b,i,k] * QT[b,i,k]
__global__ __launch_bounds__(256) void k_final_out(
    const float* __restrict__ V, const float* __restrict__ QT, float* __restrict__ out)
{
  int b = blockIdx.x >> 1;
  int k = ((blockIdx.x & 1) << 8) + threadIdx.x;
  const float* Vb = V + (long)b * N_ * D_ + k;
  const float* Tb = QT + (long)b * N_ * D_ + k;
  float acc = 0.0f;
  for (int i = 0; i < N_; ++i) acc += Vb[(long)i * D_] * Tb[(long)i * D_];
  out[b * D_ + k] = acc * (1.0f / 512.0f);
}

extern "C" void kernel_launch(void* const* d_in, const int* in_sizes, int n_in,
                              void* d_out, int out_size, void* d_ws, size_t ws_size,
                              hipStream_t stream)
{
  const float* in_v   = (const float*)d_in[0];
  const float* in_q   = (const float*)d_in[1];
  const int*   v_mask = (const int*)  d_in[2];
  const int*   q_mask = (const int*)  d_in[3];
  const float* aw  = (const float*)d_in[4];
  const float* ab  = (const float*)d_in[5];
  const float* awo = (const float*)d_in[6];
  const float* abo = (const float*)d_in[7];
  const float* lg  = (const float*)d_in[8];
  const float* lb  = (const float*)d_in[9];
  const float* fw1 = (const float*)d_in[10];
  const float* fb1 = (const float*)d_in[11];
  const float* fw2 = (const float*)d_in[12];
  const float* fb2 = (const float*)d_in[13];
  const float* atw = (const float*)d_in[14];
  const float* atb = (const float*)d_in[15];
  float* out = (float*)d_out;

  const int SZ = B_ * N_ * D_;          // 2,097,152
  char* wsb = (char*)d_ws;
  const long MB = 1024L * 1024;
  float* Vcur   = (float*)(wsb + 0 * MB);
  float* Qcur   = (float*)(wsb + 8 * MB);
  float* VQ     = (float*)(wsb + 16 * MB);
  float* T      = (float*)(wsb + 24 * MB);
  bf16*  Qp_b   = (bf16*)(wsb + 32 * MB);
  bf16*  Ob_b   = Qp_b;                 // alias: Qp dead after scores
  bf16*  Kp_b   = (bf16*)(wsb + 36 * MB);
  bf16*  Vp_t   = (bf16*)(wsb + 40 * MB);
  bf16*  Vcur_b = (bf16*)(wsb + 44 * MB);
  bf16*  Qcur_b = (bf16*)(wsb + 48 * MB);
  bf16*  VA_b   = (bf16*)(wsb + 52 * MB);
  bf16*  QA_b   = (bf16*)(wsb + 56 * MB);
  bf16*  VQ_b   = (bf16*)(wsb + 60 * MB);
  bf16*  WT     = (bf16*)(wsb + 64 * MB);   // 16 MB
  float* Sb     = (float*)(wsb + 80 * MB);  // 64 MiB
  bf16*  Hid    = (bf16*)Sb;                // FFN hidden aliases Sb

  k_prep<<<8192, 256, 0, stream>>>(in_v, Vcur, Vcur_b, SZ);
  k_prep<<<8192, 256, 0, stream>>>(in_q, Qcur, Qcur_b, SZ);

  auto mha = [&](const bf16* xq_b, const bf16* xkv_b, const int* kvm, int l, int mi,
                 float* tf, bf16* tb) {
    const bf16* WTq = WT + (long)(mi * 4 + 0) * 262144;
    const bf16* WTk = WT + (long)(mi * 4 + 1) * 262144;
    const bf16* WTv = WT + (long)(mi * 4 + 2) * 262144;
    const bf16* WTo = WT + (long)(mi * 4 + 3) * 262144;
    const float* bb = ab + (long)(l * 4 + mi) * 3 * D_;
    const float* bo = abo + (long)(l * 4 + mi) * D_;
    k_mfma<64><<<dim3(8, 32, 1), 256, 0, stream>>>(xq_b, 0, 0, 512, WTq, 0, 0, 512,
        bb, 1.f, 0, nullptr, 0, 0, 0, Qp_b, 0, 0, 512, 512, 1, 0);
    k_mfma<64><<<dim3(8, 32, 1), 256, 0, stream>>>(xkv_b, 0, 0, 512, WTk, 0, 0, 512,
        bb + 512, 1.f, 0, nullptr, 0, 0, 0, Kp_b, 0, 0, 512, 512, 1, 0);
    k_mfma<64><<<dim3(8, 32, 1), 256, 0, stream>>>(xkv_b, 0, 0, 512, WTv, 0, 0, 512,
        bb + 1024, 1.f, 0, nullptr, 0, 0, 0, Vp_t, 0, 0, 512, 512, 1, 1);
    k_mfma<128><<<dim3(4, 4, 64), 256, 0, stream>>>(Qp_b, 262144, 64, 512,
        Kp_b, 262144, 64, 512, nullptr, 0.125f, 0,
        Sb, 2097152, 262144, 512, nullptr, 0, 0, 0, 64, 8, 0);
    k_softmax_p<<<32768, 256, 0, stream>>>(Sb, kvm);
    k_mfma<64><<<dim3(1, 4, 64), 256, 0, stream>>>((const bf16*)Sb, 4194304, 524288, 1024,
        Vp_t, 262144, 32768, 512, nullptr, 1.f, 0,
        nullptr, 0, 0, 0, Ob_b, 262144, 64, 512, 512, 8, 0);
    k_mfma<64><<<dim3(8, 32, 1), 256, 0, stream>>>(Ob_b, 0, 0, 512, WTo, 0, 0, 512,
        bo, 1.f, 0, tf, 0, 0, 512, tb, 0, 0, 512, 512, 1, 0);
  };

  auto ffn = [&](const bf16* x_b, int l, int fi) {
    k_mfma<128><<<dim3(16, 32, 1), 256, 0, stream>>>(x_b, 0, 0, 512,
        WT + 4194304 + (long)fi * 1048576, 0, 0, 512,
        fb1 + (long)(l * 2 + fi) * DF_, 1.f, 1,
        nullptr, 0, 0, 0, Hid, 0, 0, 2048, 512, 1, 0);
    k_mfma<64><<<dim3(8, 32, 1), 256, 0, stream>>>(Hid, 0, 0, 2048,
        WT + 6291456 + (long)fi * 1048576, 0, 0, 2048,
        fb2 + (long)(l * 2 + fi) * D_, 1.f, 0,
        T, 0, 0, 512, nullptr, 0, 0, 0, 2048, 1, 0);
  };

  for (int l = 0; l < L_; ++l) {
    const float* lgl = lg + (long)l * 6 * D_;
    const float* lbl = lb + (long)l * 6 * D_;
    k_wt<<<8192, 256, 0, stream>>>(aw + (long)l * 12 * 262144,
                                   awo + (long)l * 4 * 262144,
                                   fw1 + (long)l * 2 * 1048576,
                                   fw2 + (long)l * 2 * 1048576, WT);
    // self-attn v
    mha(Vcur_b, Vcur_b, v_mask, l, 0, T, nullptr);
    k_ln_res<<<4096, 256, 0, stream>>>(Vcur, T, lgl + 0 * D_, lbl + 0 * D_, nullptr, VA_b);
    // self-attn q
    mha(Qcur_b, Qcur_b, q_mask, l, 1, T, nullptr);
    k_ln_res<<<4096, 256, 0, stream>>>(Qcur, T, lgl + 1 * D_, lbl + 1 * D_, nullptr, QA_b);
    // cross attention
    mha(VA_b, QA_b, q_mask, l, 2, VQ, VQ_b);
    mha(QA_b, VQ_b, v_mask, l, 3, T, nullptr);
    k_ln_res<<<4096, 256, 0, stream>>>(Vcur, VQ, lgl + 2 * D_, lbl + 2 * D_, Vcur, Vcur_b);
    k_ln_res<<<4096, 256, 0, stream>>>(Qcur, T, lgl + 3 * D_, lbl + 3 * D_, Qcur, Qcur_b);
    // FFN
    ffn(Vcur_b, l, 0);
    k_ln_res<<<4096, 256, 0, stream>>>(Vcur, T, lgl + 4 * D_, lbl + 4 * D_, Vcur, Vcur_b);
    ffn(Qcur_b, l, 1);
    k_ln_res<<<4096, 256, 0, stream>>>(Qcur, T, lgl + 5 * D_, lbl + 5 * D_, Qcur, Qcur_b);
  }

  // final bilinear attention pooling (fp32)
  dim3 blk(16, 16);
  k_final_scores<<<dim3(8, 8, 8), blk, 0, stream>>>(Vcur, Qcur, atw, atb, Sb);
  k_softmax_cross<<<4096, 256, 0, stream>>>(Sb, v_mask, q_mask);
  k_final_pm<<<dim3(8, 8, 8), blk, 0, stream>>>(Sb, Qcur, T);
  k_final_out<<<16, 256, 0, stream>>>(Vcur, T, out);

  (void)in_sizes; (void)n_in; (void)out_size; (void)ws_size;
}

// Round 4
// 1980.690 us; speedup vs baseline: 4.1021x; 1.4618x over previous
//
#include <hip/hip_runtime.h>
#include <hip/hip_bf16.h>

typedef __hip_bfloat16 bf16;
typedef __attribute__((ext_vector_type(8))) short short8;
typedef __attribute__((ext_vector_type(4))) short short4v;
typedef __attribute__((ext_vector_type(4))) float f32x4;

#define AS1 __attribute__((address_space(1)))
#define AS3 __attribute__((address_space(3)))

#define B_  8
#define N_  512
#define D_  512
#define H_  8
#define DH_ 64
#define DF_ 2048
#define L_  4

// ---------------- input prep: fp32 copy + bf16 shadow ----------------
__global__ __launch_bounds__(256) void k_prep(const float* __restrict__ in,
                                              float* __restrict__ f,
                                              bf16* __restrict__ b, int n) {
  int i = blockIdx.x * 256 + threadIdx.x;
  if (i < n) { float v = in[i]; f[i] = v; b[i] = __float2bfloat16(v); }
}

// ---------------- per-layer weight transpose + cast (same as round 3) ----------------
__global__ __launch_bounds__(256) void k_wt(const float* __restrict__ aw_l,
                                            const float* __restrict__ awo_l,
                                            const float* __restrict__ fw1_l,
                                            const float* __restrict__ fw2_l,
                                            bf16* __restrict__ WT)
{
  __shared__ float Ls[32][33];
  int bx = blockIdx.x;
  const float* src; bf16* dst; int R, C, tr, tc;
  if (bx < 4096) {
    int id = bx >> 8, t = bx & 255;
    int m = id >> 2, part = id & 3;
    src = (part < 3) ? (aw_l + ((long)m * 3 + part) * D_ * D_)
                     : (awo_l + (long)m * D_ * D_);
    dst = WT + (long)id * 262144; R = 512; C = 512; tr = t >> 4; tc = t & 15;
  } else if (bx < 6144) {
    int q = bx - 4096; int id = q >> 10; int t = q & 1023;
    src = fw1_l + (long)id * D_ * DF_; dst = WT + 4194304 + (long)id * 1048576;
    R = 512; C = 2048; tr = t >> 6; tc = t & 63;
  } else {
    int q = bx - 6144; int id = q >> 10; int t = q & 1023;
    src = fw2_l + (long)id * DF_ * D_; dst = WT + 6291456 + (long)id * 1048576;
    R = 2048; C = 512; tr = t >> 4; tc = t & 15;
  }
  int tt = threadIdx.x;
#pragma unroll
  for (int p = 0; p < 4; ++p) {
    int idx = tt + p * 256; int lr = idx >> 5, lc = idx & 31;
    Ls[lr][lc] = src[(long)(tr * 32 + lr) * C + tc * 32 + lc];
  }
  __syncthreads();
#pragma unroll
  for (int p = 0; p < 4; ++p) {
    int idx = tt + p * 256; int lr = idx >> 5, lc = idx & 31;
    dst[(long)(tc * 32 + lr) * R + tr * 32 + lc] = __float2bfloat16(Ls[lc][lr]);
  }
}

// ---------------- MFMA GEMM, m97 structure. C = A @ B^T, both [rows][K-contig] bf16.
// z -> (s = z/zPerS stream, zz = z%zPerS -> zb = zz/Hh, zh = zz%Hh).
// mode 0: normal epilogue (fp32 Cf and/or bf16 Cb). mode 1: fused-QKV routing:
//   A for blockIdx.x<8 (q-proj), A2 otherwise (k/v-proj); Cb = QKV stream base:
//   cols 0-511 -> Q slot, 512-1023 -> K slot, 1024-1535 -> V transposed [b][h][d][tok].
template<int BN>
__global__ __launch_bounds__(256, 2) void k_mfma(
    const bf16* __restrict__ A, const bf16* __restrict__ A2,
    long aS, long aB, long aH, int lda,
    const bf16* __restrict__ Bm, long bS, long bB, long bH, int ldb,
    const float* __restrict__ bias, long biasS, float scale, int relu,
    float* __restrict__ Cf, long cfS, long cfB, long cfH, int ldcf,
    bf16* __restrict__ Cb, long cbS, long cbB, long cbH, int ldcb,
    int K, int Hh, int zPerS, int mode)
{
  constexpr int MI = (BN == 128) ? 4 : 2;
  constexpr int NI = 4;
  __shared__ short As[128 * 32];
  __shared__ short Bs[BN * 32];
  int tid = threadIdx.x;
  int w = tid >> 6, lane = tid & 63;
  int z = blockIdx.z;
  int s = z / zPerS; int zz = z - s * zPerS;
  int zb = zz / Hh, zh = zz - zb * Hh;
  const bf16* Asel = (mode == 1 && blockIdx.x >= 8) ? A2 : A;
  const bf16* Ab = Asel + s * aS + zb * aB + zh * aH;
  const bf16* Bb = Bm + s * bS + zb * bB + zh * bH;
  int row0 = blockIdx.y * 128;
  int col0 = blockIdx.x * BN;
  int rw = (BN == 128) ? ((w >> 1) * 64) : (w * 32);
  int cw = (BN == 128) ? ((w & 1) * 64) : 0;
  int quad = lane >> 4, l16 = lane & 15;

  f32x4 acc[MI][NI];
#pragma unroll
  for (int i = 0; i < MI; ++i)
#pragma unroll
    for (int j = 0; j < NI; ++j) acc[i][j] = {0.f, 0.f, 0.f, 0.f};

  for (int k0 = 0; k0 < K; k0 += 32) {
#pragma unroll
    for (int i = 0; i < 2; ++i) {
      int o = i * 4096 + w * 1024 + lane * 16;
      int r = o >> 6;
      const bf16* g = Ab + (long)(row0 + r) * lda + k0 + ((o & 63) >> 1);
      char* lp = (char*)As + i * 4096 + w * 1024;
      __builtin_amdgcn_global_load_lds((const AS1 void*)g, (AS3 void*)lp, 16, 0, 0);
    }
    constexpr int BI = (BN == 128) ? 2 : 1;
#pragma unroll
    for (int i = 0; i < BI; ++i) {
      int o = i * 4096 + w * 1024 + lane * 16;
      int r = o >> 6;
      const bf16* g = Bb + (long)(col0 + r) * ldb + k0 + ((o & 63) >> 1);
      char* lp = (char*)Bs + i * 4096 + w * 1024;
      __builtin_amdgcn_global_load_lds((const AS1 void*)g, (AS3 void*)lp, 16, 0, 0);
    }
    __syncthreads();
    short8 af[MI], bfr[NI];
#pragma unroll
    for (int mi = 0; mi < MI; ++mi)
      af[mi] = *(const short8*)&As[(rw + mi * 16 + l16) * 32 + quad * 8];
#pragma unroll
    for (int ni = 0; ni < NI; ++ni)
      bfr[ni] = *(const short8*)&Bs[(cw + ni * 16 + l16) * 32 + quad * 8];
#pragma unroll
    for (int mi = 0; mi < MI; ++mi)
#pragma unroll
      for (int ni = 0; ni < NI; ++ni)
        acc[mi][ni] = __builtin_amdgcn_mfma_f32_16x16x32_bf16(af[mi], bfr[ni], acc[mi][ni], 0, 0, 0);
    __syncthreads();
  }

  const float* bp = bias ? bias + s * biasS : nullptr;
#pragma unroll
  for (int mi = 0; mi < MI; ++mi)
#pragma unroll
    for (int ni = 0; ni < NI; ++ni) {
      int cg = col0 + cw + ni * 16 + l16;
      float bv = bp ? bp[cg] : 0.0f;
#pragma unroll
      for (int r = 0; r < 4; ++r) {
        int rg = row0 + rw + mi * 16 + quad * 4 + r;
        float v = acc[mi][ni][r] * scale + bv;
        if (relu) v = fmaxf(v, 0.0f);
        if (mode == 1) {
          bf16* base = Cb + s * cbS;
          if (cg < 512) base[(long)rg * 512 + cg] = __float2bfloat16(v);
          else if (cg < 1024) base[2097152 + (long)rg * 512 + (cg - 512)] = __float2bfloat16(v);
          else {
            int c2 = cg - 1024;
            base[4194304 + ((long)((rg >> 9) * 8 + (c2 >> 6)) * 64 + (c2 & 63)) * 512 + (rg & 511)]
                = __float2bfloat16(v);
          }
        } else {
          if (Cf) Cf[s * cfS + zb * cfB + zh * cfH + (long)rg * ldcf + cg] = v;
          if (Cb) Cb[s * cbS + zb * cbB + zh * cbH + (long)rg * ldcb + cg] = __float2bfloat16(v);
        }
      }
    }
}

// ---------------- wave-per-row masked softmax (512 cols), bf16 probs in-place ----------------
__global__ __launch_bounds__(256) void k_softmax_w(float* __restrict__ S,
                                                   const int* __restrict__ kvm)
{
  int wrow = blockIdx.x * 4 + (threadIdx.x >> 6);
  int lane = threadIdx.x & 63;
  float* p = S + (long)wrow * 512;
  const int* mb = kvm + ((wrow >> 12) << 9);
  int j0 = lane * 8;
  float4 a0 = *(const float4*)(p + j0);
  float4 a1 = *(const float4*)(p + j0 + 4);
  int4 m0 = *(const int4*)(mb + j0);
  int4 m1 = *(const int4*)(mb + j0 + 4);
  float v[8];
  v[0] = m0.x ? a0.x : -1e9f; v[1] = m0.y ? a0.y : -1e9f;
  v[2] = m0.z ? a0.z : -1e9f; v[3] = m0.w ? a0.w : -1e9f;
  v[4] = m1.x ? a1.x : -1e9f; v[5] = m1.y ? a1.y : -1e9f;
  v[6] = m1.z ? a1.z : -1e9f; v[7] = m1.w ? a1.w : -1e9f;
  float mx = v[0];
#pragma unroll
  for (int u = 1; u < 8; ++u) mx = fmaxf(mx, v[u]);
#pragma unroll
  for (int o = 1; o < 64; o <<= 1) mx = fmaxf(mx, __shfl_xor(mx, o, 64));
  float e[8], sum = 0.f;
#pragma unroll
  for (int u = 0; u < 8; ++u) { e[u] = __expf(v[u] - mx); sum += e[u]; }
#pragma unroll
  for (int o = 1; o < 64; o <<= 1) sum += __shfl_xor(sum, o, 64);
  float inv = 1.0f / sum;
  bf16 ob[8];
#pragma unroll
  for (int u = 0; u < 8; ++u) ob[u] = __float2bfloat16(e[u] * inv);
  bf16* pb = (bf16*)p;
  *(short8*)&pb[j0] = *(const short8*)ob;
}

// ---------------- wave-per-row cross-masked softmax (final pooling) ----------------
__global__ __launch_bounds__(256) void k_softmax_x(float* __restrict__ S,
                                                   const int* __restrict__ vm,
                                                   const int* __restrict__ qm)
{
  int wrow = blockIdx.x * 4 + (threadIdx.x >> 6);
  int lane = threadIdx.x & 63;
  int b = wrow >> 9, i = wrow & 511;
  bool rowpad = (vm[(b << 9) + i] == 0);
  float* p = S + (long)wrow * 512;
  const int* qb = qm + (b << 9);
  int j0 = lane * 8;
  float4 a0 = *(const float4*)(p + j0);
  float4 a1 = *(const float4*)(p + j0 + 4);
  int4 m0 = *(const int4*)(qb + j0);
  int4 m1 = *(const int4*)(qb + j0 + 4);
  float v[8];
  v[0] = (rowpad || !m0.x) ? -1e9f : a0.x; v[1] = (rowpad || !m0.y) ? -1e9f : a0.y;
  v[2] = (rowpad || !m0.z) ? -1e9f : a0.z; v[3] = (rowpad || !m0.w) ? -1e9f : a0.w;
  v[4] = (rowpad || !m1.x) ? -1e9f : a1.x; v[5] = (rowpad || !m1.y) ? -1e9f : a1.y;
  v[6] = (rowpad || !m1.z) ? -1e9f : a1.z; v[7] = (rowpad || !m1.w) ? -1e9f : a1.w;
  float mx = v[0];
#pragma unroll
  for (int u = 1; u < 8; ++u) mx = fmaxf(mx, v[u]);
#pragma unroll
  for (int o = 1; o < 64; o <<= 1) mx = fmaxf(mx, __shfl_xor(mx, o, 64));
  float e[8], sum = 0.f;
#pragma unroll
  for (int u = 0; u < 8; ++u) { e[u] = __expf(v[u] - mx); sum += e[u]; }
#pragma unroll
  for (int o = 1; o < 64; o <<= 1) sum += __shfl_xor(sum, o, 64);
  float inv = 1.0f / sum;
  bf16 ob[8];
#pragma unroll
  for (int u = 0; u < 8; ++u) ob[u] = __float2bfloat16(e[u] * inv);
  bf16* pb = (bf16*)p;
  *(short8*)&pb[j0] = *(const short8*)ob;
}

// ---------------- fused dual LN: y = LN(x + r) * g + b, 2 independent streams ----------------
__global__ __launch_bounds__(256) void k_ln2(
    const float* x0, const float* r0, const float* g0, const float* b0,
    float* yf0, bf16* yb0,
    const float* x1, const float* r1, const float* g1, const float* b1,
    float* yf1, bf16* yb1)
{
  int sel = blockIdx.x >> 12;
  long row = blockIdx.x & 4095;
  const float* x = sel ? x1 : x0;
  const float* r = sel ? r1 : r0;
  const float* g = sel ? g1 : g0;
  const float* bb = sel ? b1 : b0;
  float* yf = sel ? yf1 : yf0;
  bf16* yb = sel ? yb1 : yb0;
  int t = threadIdx.x;
  const float* xr = x + row * D_;
  const float* rr = r + row * D_;
  float v0 = xr[t] + rr[t];
  float v1 = xr[t + 256] + rr[t + 256];
  float s = v0 + v1;
  float ss = v0 * v0 + v1 * v1;
#pragma unroll
  for (int o = 32; o > 0; o >>= 1) {
    s += __shfl_down(s, o, 64);
    ss += __shfl_down(ss, o, 64);
  }
  __shared__ float rs[4];
  __shared__ float rss[4];
  int lane = t & 63, wid = t >> 6;
  if (lane == 0) { rs[wid] = s; rss[wid] = ss; }
  __syncthreads();
  s = rs[0] + rs[1] + rs[2] + rs[3];
  ss = rss[0] + rss[1] + rss[2] + rss[3];
  float mean = s * (1.0f / D_);
  float var = ss * (1.0f / D_) - mean * mean;
  float rstd = rsqrtf(var + 1e-5f);
  float o0 = (v0 - mean) * rstd * g[t]       + bb[t];
  float o1 = (v1 - mean) * rstd * g[t + 256] + bb[t + 256];
  if (yf) { float* yr = yf + row * D_; yr[t] = o0; yr[t + 256] = o1; }
  if (yb) { bf16* yr = yb + row * D_; yr[t] = __float2bfloat16(o0); yr[t + 256] = __float2bfloat16(o1); }
}

// ---------------- final prep: Vw = bf16(V*w) elementwise; Qt = bf16(Q^T) per batch ----------------
__global__ __launch_bounds__(256) void k_vwqt(const float* __restrict__ V,
                                              const float* __restrict__ Q,
                                              const float* __restrict__ w,
                                              bf16* __restrict__ Vw, bf16* __restrict__ Qt)
{
  __shared__ float Ls[32][33];
  int bx = blockIdx.x, t = threadIdx.x;
  if (bx < 2048) {
    int i = bx * 1024 + t * 4;
    float4 v = *(const float4*)(V + i);
    int k = i & 511;
    bf16 o[4] = { __float2bfloat16(v.x * w[k]),     __float2bfloat16(v.y * w[k + 1]),
                  __float2bfloat16(v.z * w[k + 2]), __float2bfloat16(v.w * w[k + 3]) };
    *(short4v*)&Vw[i] = *(const short4v*)o;
  } else {
    int q = bx - 2048; int b = q >> 8; int tq = q & 255;
    int tr = tq >> 4, tc = tq & 15;
    const float* Qb = Q + (long)b * 262144;
    bf16* Qtb = Qt + (long)b * 262144;
#pragma unroll
    for (int p = 0; p < 4; ++p) {
      int idx = t + p * 256; int lr = idx >> 5, lc = idx & 31;
      Ls[lr][lc] = Qb[(long)(tr * 32 + lr) * 512 + tc * 32 + lc];
    }
    __syncthreads();
#pragma unroll
    for (int p = 0; p < 4; ++p) {
      int idx = t + p * 256; int lr = idx >> 5, lc = idx & 31;
      Qtb[(long)(tc * 32 + lr) * 512 + tr * 32 + lc] = __float2bfloat16(Ls[lc][lr]);
    }
  }
}

// ---------------- out[b,k] = (1/512) * sum_i V[b,i,k] * T[b,i,k] ----------------
__global__ __launch_bounds__(256) void k_final_out(
    const float* __restrict__ V, const float* __restrict__ QT, float* __restrict__ out)
{
  int b = blockIdx.x >> 1;
  int k = ((blockIdx.x & 1) << 8) + threadIdx.x;
  const float* Vb = V + (long)b * N_ * D_ + k;
  const float* Tb = QT + (long)b * N_ * D_ + k;
  float acc = 0.0f;
  for (int i = 0; i < N_; ++i) acc += Vb[(long)i * D_] * Tb[(long)i * D_];
  out[b * D_ + k] = acc * (1.0f / 512.0f);
}

extern "C" void kernel_launch(void* const* d_in, const int* in_sizes, int n_in,
                              void* d_out, int out_size, void* d_ws, size_t ws_size,
                              hipStream_t stream)
{
  const float* in_v   = (const float*)d_in[0];
  const float* in_q   = (const float*)d_in[1];
  const int*   v_mask = (const int*)  d_in[2];
  const int*   q_mask = (const int*)  d_in[3];
  const float* aw  = (const float*)d_in[4];
  const float* ab  = (const float*)d_in[5];
  const float* awo = (const float*)d_in[6];
  const float* abo = (const float*)d_in[7];
  const float* lg  = (const float*)d_in[8];
  const float* lb  = (const float*)d_in[9];
  const float* fw1 = (const float*)d_in[10];
  const float* fb1 = (const float*)d_in[11];
  const float* fw2 = (const float*)d_in[12];
  const float* fb2 = (const float*)d_in[13];
  const float* atw = (const float*)d_in[14];
  const float* atb = (const float*)d_in[15];
  float* out = (float*)d_out;
  (void)atb;  // softmax is shift-invariant -> scalar bias dropped

  const int SZ = B_ * N_ * D_;
  char* wsb = (char*)d_ws;
  const long MB = 1024L * 1024;
  // Layout (MB): 0 Vcur(8) | 8 Qcur(8) | 16 T(8) | 24 WT(16) | 40 Vcur_b(4) |
  // 44 Qcur_b(4) | 48 VA_b(4) | 52 QA_b(4) | 56 QKV 2 streams x {Q,K,Vt} (24) |
  // [68 VQ_b / 72 Vw_b / 76 Qt_b alias QKV s1] | 80 Sb(64, Hid/T2 alias). Total 144.
  float* Vcur   = (float*)(wsb + 0 * MB);
  float* Qcur   = (float*)(wsb + 8 * MB);
  float* T      = (float*)(wsb + 16 * MB);
  bf16*  WT     = (bf16*) (wsb + 24 * MB);
  bf16*  Vcur_b = (bf16*) (wsb + 40 * MB);
  bf16*  Qcur_b = (bf16*) (wsb + 44 * MB);
  bf16*  VA_b   = (bf16*) (wsb + 48 * MB);
  bf16*  QA_b   = (bf16*) (wsb + 52 * MB);
  bf16*  QKV0   = (bf16*) (wsb + 56 * MB);
  bf16*  VQ_b   = (bf16*) (wsb + 68 * MB);
  bf16*  Vw_b   = (bf16*) (wsb + 72 * MB);
  bf16*  Qt_b   = (bf16*) (wsb + 76 * MB);
  float* SbF    = (float*)(wsb + 80 * MB);
  bf16*  Hid    = (bf16*) SbF;
  float* T2f    = (float*)(wsb + 112 * MB);

  const long ZBIG = 1000000;

  k_prep<<<8192, 256, 0, stream>>>(in_v, Vcur, Vcur_b, SZ);
  k_prep<<<8192, 256, 0, stream>>>(in_q, Qcur, Qcur_b, SZ);

  // scores -> softmax -> PV for one stream s (QKV slots), mask kvm
  auto attn_core = [&](int s, const int* kvm) {
    bf16* Qs = QKV0 + (long)s * 6291456;
    bf16* Ks = Qs + 2097152;
    bf16* Vt = Qs + 4194304;
    k_mfma<128><<<dim3(4, 4, 64), 256, 0, stream>>>(
        Qs, Qs, 0, 262144, 64, 512, Ks, 0, 262144, 64, 512,
        nullptr, 0, 0.125f, 0,
        SbF, 0, 2097152, 262144, 512, nullptr, 0, 0, 0, 0,
        64, 8, ZBIG, 0);
    k_softmax_w<<<8192, 256, 0, stream>>>(SbF, kvm);
    k_mfma<64><<<dim3(1, 4, 64), 256, 0, stream>>>(
        (const bf16*)SbF, (const bf16*)SbF, 0, 4194304, 524288, 1024,
        Vt, 0, 262144, 32768, 512,
        nullptr, 0, 1.f, 0,
        nullptr, 0, 0, 0, 0, Qs /*Ob overwrites dead Q slot*/, 0, 262144, 64, 512,
        512, 8, ZBIG, 0);
  };

  for (int l = 0; l < L_; ++l) {
    const float* lgl = lg + (long)l * 6 * D_;
    const float* lbl = lb + (long)l * 6 * D_;
    k_wt<<<8192, 256, 0, stream>>>(aw + (long)l * 12 * 262144,
                                   awo + (long)l * 4 * 262144,
                                   fw1 + (long)l * 2 * 1048576,
                                   fw2 + (long)l * 2 * 1048576, WT);
    // ---- self-attention, both streams batched where independent ----
    k_mfma<64><<<dim3(24, 32, 2), 256, 0, stream>>>(        // QKV: s0=v, s1=q
        Vcur_b, Vcur_b, 2097152, 0, 0, 512,
        WT, 1048576, 0, 0, 512,
        ab + (long)l * 4 * 1536, 1536, 1.f, 0,
        nullptr, 0, 0, 0, 0, QKV0, 6291456, 0, 0, 0,
        512, 1, 1, 1);
    attn_core(0, v_mask);
    attn_core(1, q_mask);
    k_mfma<64><<<dim3(8, 32, 2), 256, 0, stream>>>(         // out-proj batched
        QKV0, QKV0, 6291456, 0, 0, 512,
        WT + 3 * 262144, 1048576, 0, 0, 512,
        abo + (long)l * 4 * 512, 512, 1.f, 0,
        T, 16777216, 0, 0, 512, nullptr, 0, 0, 0, 0,
        512, 1, 1, 0);
    k_ln2<<<8192, 256, 0, stream>>>(Vcur, T,   lgl + 0 * D_, lbl + 0 * D_, nullptr, VA_b,
                                    Qcur, SbF, lgl + 1 * D_, lbl + 1 * D_, nullptr, QA_b);
    // ---- cross attention: vq (mi=2), then qv (mi=3) ----
    k_mfma<64><<<dim3(24, 32, 1), 256, 0, stream>>>(        // QKV cross: xq=VA, xkv=QA
        VA_b, QA_b, 0, 0, 0, 512,
        WT + 2 * 1048576, 0, 0, 0, 512,
        ab + (long)(l * 4 + 2) * 1536, 0, 1.f, 0,
        nullptr, 0, 0, 0, 0, QKV0, 0, 0, 0, 0,
        512, 1, 1, 1);
    attn_core(0, q_mask);
    k_mfma<64><<<dim3(8, 32, 1), 256, 0, stream>>>(         // out-proj -> T fp32 + VQ_b bf16
        QKV0, QKV0, 0, 0, 0, 512,
        WT + (2 * 4 + 3) * 262144, 0, 0, 0, 512,
        abo + (long)(l * 4 + 2) * 512, 0, 1.f, 0,
        T, 0, 0, 0, 512, VQ_b, 0, 0, 0, 512,
        512, 1, 1, 0);
    k_mfma<64><<<dim3(24, 32, 1), 256, 0, stream>>>(        // QKV cross: xq=QA, xkv=VQ
        QA_b, VQ_b, 0, 0, 0, 512,
        WT + 3 * 1048576, 0, 0, 0, 512,
        ab + (long)(l * 4 + 3) * 1536, 0, 1.f, 0,
        nullptr, 0, 0, 0, 0, QKV0, 0, 0, 0, 0,
        512, 1, 1, 1);
    attn_core(0, v_mask);
    k_mfma<64><<<dim3(8, 32, 1), 256, 0, stream>>>(         // out-proj -> SbF fp32
        QKV0, QKV0, 0, 0, 0, 512,
        WT + (3 * 4 + 3) * 262144, 0, 0, 0, 512,
        abo + (long)(l * 4 + 3) * 512, 0, 1.f, 0,
        SbF, 0, 0, 0, 512, nullptr, 0, 0, 0, 0,
        512, 1, 1, 0);
    k_ln2<<<8192, 256, 0, stream>>>(Vcur, T,   lgl + 2 * D_, lbl + 2 * D_, Vcur, Vcur_b,
                                    Qcur, SbF, lgl + 3 * D_, lbl + 3 * D_, Qcur, Qcur_b);
    // ---- FFN, both streams batched ----
    k_mfma<128><<<dim3(16, 32, 2), 256, 0, stream>>>(       // fc1 + relu -> Hid
        Vcur_b, Vcur_b, 2097152, 0, 0, 512,
        WT + 4194304, 1048576, 0, 0, 512,
        fb1 + (long)l * 2 * 2048, 2048, 1.f, 1,
        nullptr, 0, 0, 0, 0, Hid, 8388608, 0, 0, 2048,
        512, 1, 1, 0);
    k_mfma<64><<<dim3(8, 32, 2), 256, 0, stream>>>(         // fc2 -> T (s0) / T2f (s1)
        Hid, Hid, 8388608, 0, 0, 2048,
        WT + 6291456, 1048576, 0, 0, 2048,
        fb2 + (long)l * 2 * 512, 512, 1.f, 0,
        T, 25165824, 0, 0, 512, nullptr, 0, 0, 0, 0,
        2048, 1, 1, 0);
    k_ln2<<<8192, 256, 0, stream>>>(Vcur, T,   lgl + 4 * D_, lbl + 4 * D_, Vcur, Vcur_b,
                                    Qcur, T2f, lgl + 5 * D_, lbl + 5 * D_, Qcur, Qcur_b);
  }

  // ---- final bilinear attention pooling, MFMA path ----
  k_vwqt<<<4096, 256, 0, stream>>>(Vcur, Qcur, atw, Vw_b, Qt_b);
  k_mfma<128><<<dim3(4, 4, 8), 256, 0, stream>>>(          // scores = (V*w) @ Q^T
      Vw_b, Vw_b, 0, 262144, 0, 512, Qcur_b, 0, 262144, 0, 512,
      nullptr, 0, 1.f, 0,
      SbF, 0, 262144, 0, 512, nullptr, 0, 0, 0, 0,
      512, 1, ZBIG, 0);
  k_softmax_x<<<1024, 256, 0, stream>>>(SbF, v_mask, q_mask);
  k_mfma<128><<<dim3(4, 4, 8), 256, 0, stream>>>(          // T = P @ Q  (B = Q^T rows=dim)
      (const bf16*)SbF, (const bf16*)SbF, 0, 524288, 0, 1024, Qt_b, 0, 262144, 0, 512,
      nullptr, 0, 1.f, 0,
      T, 0, 262144, 0, 512, nullptr, 0, 0, 0, 0,
      512, 1, ZBIG, 0);
  k_final_out<<<16, 256, 0, stream>>>(Vcur, T, out);

  (void)in_sizes; (void)n_in; (void)out_size; (void)ws_size;
}

// Round 5
// 1570.710 us; speedup vs baseline: 5.1728x; 1.2610x over previous
//
#include <hip/hip_runtime.h>
#include <hip/hip_bf16.h>

typedef __hip_bfloat16 bf16;
typedef __attribute__((ext_vector_type(8))) short short8;
typedef __attribute__((ext_vector_type(4))) short short4v;
typedef __attribute__((ext_vector_type(4))) float f32x4;

#define AS1 __attribute__((address_space(1)))
#define AS3 __attribute__((address_space(3)))

#define B_  8
#define N_  512
#define D_  512
#define H_  8
#define DH_ 64
#define DF_ 2048
#define L_  4

static __device__ __forceinline__ short bfbits(float x) {
  bf16 t = __float2bfloat16(x);
  return *reinterpret_cast<short*>(&t);
}

// ---------------- input prep: fp32 copy + bf16 shadow ----------------
__global__ __launch_bounds__(256) void k_prep(const float* __restrict__ in,
                                              float* __restrict__ f,
                                              bf16* __restrict__ b, int n) {
  int i = blockIdx.x * 256 + threadIdx.x;
  if (i < n) { float v = in[i]; f[i] = v; b[i] = __float2bfloat16(v); }
}

// ---------------- per-layer weight transpose + cast ----------------
__global__ __launch_bounds__(256) void k_wt(const float* __restrict__ aw_l,
                                            const float* __restrict__ awo_l,
                                            const float* __restrict__ fw1_l,
                                            const float* __restrict__ fw2_l,
                                            bf16* __restrict__ WT)
{
  __shared__ float Ls[32][33];
  int bx = blockIdx.x;
  const float* src; bf16* dst; int R, C, tr, tc;
  if (bx < 4096) {
    int id = bx >> 8, t = bx & 255;
    int m = id >> 2, part = id & 3;
    src = (part < 3) ? (aw_l + ((long)m * 3 + part) * D_ * D_)
                     : (awo_l + (long)m * D_ * D_);
    dst = WT + (long)id * 262144; R = 512; C = 512; tr = t >> 4; tc = t & 15;
  } else if (bx < 6144) {
    int q = bx - 4096; int id = q >> 10; int t = q & 1023;
    src = fw1_l + (long)id * D_ * DF_; dst = WT + 4194304 + (long)id * 1048576;
    R = 512; C = 2048; tr = t >> 6; tc = t & 63;
  } else {
    int q = bx - 6144; int id = q >> 10; int t = q & 1023;
    src = fw2_l + (long)id * DF_ * D_; dst = WT + 6291456 + (long)id * 1048576;
    R = 2048; C = 512; tr = t >> 4; tc = t & 15;
  }
  int tt = threadIdx.x;
#pragma unroll
  for (int p = 0; p < 4; ++p) {
    int idx = tt + p * 256; int lr = idx >> 5, lc = idx & 31;
    Ls[lr][lc] = src[(long)(tr * 32 + lr) * C + tc * 32 + lc];
  }
  __syncthreads();
#pragma unroll
  for (int p = 0; p < 4; ++p) {
    int idx = tt + p * 256; int lr = idx >> 5, lc = idx & 31;
    dst[(long)(tc * 32 + lr) * R + tr * 32 + lc] = __float2bfloat16(Ls[lc][lr]);
  }
}

// ---------------- MFMA GEMM (m97 structure). C = A @ B^T, both [rows][K-contig] bf16.
// mode 1 = fused QKV routing (A for cols<512 [q], A2 otherwise [k,v]; V transposed out).
template<int BN>
__global__ __launch_bounds__(256, 2) void k_mfma(
    const bf16* __restrict__ A, const bf16* __restrict__ A2,
    long aS, long aB, long aH, int lda,
    const bf16* __restrict__ Bm, long bS, long bB, long bH, int ldb,
    const float* __restrict__ bias, long biasS, float scale, int relu,
    float* __restrict__ Cf, long cfS, long cfB, long cfH, int ldcf,
    bf16* __restrict__ Cb, long cbS, long cbB, long cbH, int ldcb,
    int K, int Hh, int zPerS, int mode)
{
  constexpr int MI = (BN == 128) ? 4 : 2;
  constexpr int NI = 4;
  __shared__ short As[128 * 32];
  __shared__ short Bs[BN * 32];
  int tid = threadIdx.x;
  int w = tid >> 6, lane = tid & 63;
  int z = blockIdx.z;
  int s = z / zPerS; int zz = z - s * zPerS;
  int zb = zz / Hh, zh = zz - zb * Hh;
  int row0 = blockIdx.y * 128;
  int col0 = blockIdx.x * BN;
  const bf16* Asel = (mode == 1 && col0 >= 512) ? A2 : A;
  const bf16* Ab = Asel + s * aS + zb * aB + zh * aH;
  const bf16* Bb = Bm + s * bS + zb * bB + zh * bH;
  int rw = (BN == 128) ? ((w >> 1) * 64) : (w * 32);
  int cw = (BN == 128) ? ((w & 1) * 64) : 0;
  int quad = lane >> 4, l16 = lane & 15;

  f32x4 acc[MI][NI];
#pragma unroll
  for (int i = 0; i < MI; ++i)
#pragma unroll
    for (int j = 0; j < NI; ++j) acc[i][j] = {0.f, 0.f, 0.f, 0.f};

  for (int k0 = 0; k0 < K; k0 += 32) {
#pragma unroll
    for (int i = 0; i < 2; ++i) {
      int o = i * 4096 + w * 1024 + lane * 16;
      int r = o >> 6;
      const bf16* g = Ab + (long)(row0 + r) * lda + k0 + ((o & 63) >> 1);
      char* lp = (char*)As + i * 4096 + w * 1024;
      __builtin_amdgcn_global_load_lds((const AS1 void*)g, (AS3 void*)lp, 16, 0, 0);
    }
    constexpr int BI = (BN == 128) ? 2 : 1;
#pragma unroll
    for (int i = 0; i < BI; ++i) {
      int o = i * 4096 + w * 1024 + lane * 16;
      int r = o >> 6;
      const bf16* g = Bb + (long)(col0 + r) * ldb + k0 + ((o & 63) >> 1);
      char* lp = (char*)Bs + i * 4096 + w * 1024;
      __builtin_amdgcn_global_load_lds((const AS1 void*)g, (AS3 void*)lp, 16, 0, 0);
    }
    __syncthreads();
    short8 af[MI], bfr[NI];
#pragma unroll
    for (int mi = 0; mi < MI; ++mi)
      af[mi] = *(const short8*)&As[(rw + mi * 16 + l16) * 32 + quad * 8];
#pragma unroll
    for (int ni = 0; ni < NI; ++ni)
      bfr[ni] = *(const short8*)&Bs[(cw + ni * 16 + l16) * 32 + quad * 8];
#pragma unroll
    for (int mi = 0; mi < MI; ++mi)
#pragma unroll
      for (int ni = 0; ni < NI; ++ni)
        acc[mi][ni] = __builtin_amdgcn_mfma_f32_16x16x32_bf16(af[mi], bfr[ni], acc[mi][ni], 0, 0, 0);
    __syncthreads();
  }

  const float* bp = bias ? bias + s * biasS : nullptr;
#pragma unroll
  for (int mi = 0; mi < MI; ++mi)
#pragma unroll
    for (int ni = 0; ni < NI; ++ni) {
      int cg = col0 + cw + ni * 16 + l16;
      float bv = bp ? bp[cg] : 0.0f;
#pragma unroll
      for (int r = 0; r < 4; ++r) {
        int rg = row0 + rw + mi * 16 + quad * 4 + r;
        float v = acc[mi][ni][r] * scale + bv;
        if (relu) v = fmaxf(v, 0.0f);
        if (mode == 1) {
          bf16* base = Cb + s * cbS;
          if (cg < 512) base[(long)rg * 512 + cg] = __float2bfloat16(v);
          else if (cg < 1024) base[2097152 + (long)rg * 512 + (cg - 512)] = __float2bfloat16(v);
          else {
            int c2 = cg - 1024;
            base[4194304 + ((long)((rg >> 9) * 8 + (c2 >> 6)) * 64 + (c2 & 63)) * 512 + (rg & 511)]
                = __float2bfloat16(v);
          }
        } else {
          if (Cf) Cf[s * cfS + zb * cfB + zh * cfH + (long)rg * ldcf + cg] = v;
          if (Cb) Cb[s * cbS + zb * cbB + zh * cbH + (long)rg * ldcb + cg] = __float2bfloat16(v);
        }
      }
    }
}

// ---------------- flash attention: O = softmax(mask(QK^T/8)) @ V, never materializing S.
// grid (qt 0..7, bh 0..63, stream). Q,K: [4096][512] bf16; Vt: [(b*8+h)*64+d][512].
// O written in-place into the Q slot (each block overwrites exactly the Q region it read).
__global__ __launch_bounds__(256, 2) void k_flash(
    const bf16* __restrict__ QKV, long sStride,
    const int* __restrict__ km0, const int* __restrict__ km1, float scale)
{
  __shared__ short Ks[2 * 128 * 32];   // [kc d-chunk][tok 128][32]
  __shared__ short Vs[4 * 64 * 32];    // [kc' tok-chunk][d 64][32]
  __shared__ short Ps[4 * 64 * 32];    // [kc' tok-chunk][q 64][32]
  int tid = threadIdx.x, w = tid >> 6, lane = tid & 63;
  int quad = lane >> 4, l16 = lane & 15;
  int s = blockIdx.z;
  const bf16* base = QKV + s * sStride;
  int bh = blockIdx.y, b = bh >> 3, h = bh & 7;
  int qt = blockIdx.x;
  const int* km = (s ? km1 : km0) + (b << 9);
  const bf16* Kg = base + 2097152;
  const bf16* Vt = base + 4194304;
  bf16* Og = (bf16*)base;

  // Q fragments (held in registers for the whole block)
  int qrow = (b << 9) + (qt << 6) + (w << 4) + l16;
  short8 qf[2];
  qf[0] = *(const short8*)&base[(long)qrow * 512 + h * 64 + quad * 8];
  qf[1] = *(const short8*)&base[(long)qrow * 512 + h * 64 + 32 + quad * 8];

  float m_[4], l_[4];
  f32x4 acc_o[4];
#pragma unroll
  for (int r = 0; r < 4; ++r) { m_[r] = -3e38f; l_[r] = 0.f; }
#pragma unroll
  for (int ni = 0; ni < 4; ++ni) acc_o[ni] = {0.f, 0.f, 0.f, 0.f};

  for (int kt = 0; kt < 4; ++kt) {
    __syncthreads();   // prior-iteration Ps/Vs reads complete before restaging
#pragma unroll
    for (int i = 0; i < 4; ++i) {          // K tile: 16 KB
      int o = i * 4096 + w * 1024 + lane * 16;
      int kc = o >> 13, rem = o & 8191;
      int n = rem >> 6, cb = rem & 63;
      const bf16* g = Kg + ((long)((b << 9) + kt * 128 + n) << 9) + h * 64 + kc * 32 + (cb >> 1);
      char* lp = (char*)Ks + i * 4096 + w * 1024;
      __builtin_amdgcn_global_load_lds((const AS1 void*)g, (AS3 void*)lp, 16, 0, 0);
    }
#pragma unroll
    for (int i = 0; i < 4; ++i) {          // V tile: 16 KB
      int o = i * 4096 + w * 1024 + lane * 16;
      int kc = o >> 12, rem = o & 4095;
      int d = rem >> 6, cb = rem & 63;
      const bf16* g = Vt + ((long)((bh << 6) + d) << 9) + kt * 128 + kc * 32 + (cb >> 1);
      char* lp = (char*)Vs + i * 4096 + w * 1024;
      __builtin_amdgcn_global_load_lds((const AS1 void*)g, (AS3 void*)lp, 16, 0, 0);
    }
    __syncthreads();
    // scores: 64 q-rows x 128 k-cols per block; wave w owns q rows w*16..+15
    f32x4 sa[8];
#pragma unroll
    for (int ni = 0; ni < 8; ++ni) sa[ni] = {0.f, 0.f, 0.f, 0.f};
#pragma unroll
    for (int kc = 0; kc < 2; ++kc)
#pragma unroll
      for (int ni = 0; ni < 8; ++ni) {
        short8 bfrag = *(const short8*)&Ks[kc * 4096 + (ni * 16 + l16) * 32 + quad * 8];
        sa[ni] = __builtin_amdgcn_mfma_f32_16x16x32_bf16(qf[kc], bfrag, sa[ni], 0, 0, 0);
      }
    float sv[8][4];
#pragma unroll
    for (int ni = 0; ni < 8; ++ni) {
      int kmv = km[kt * 128 + ni * 16 + l16];
#pragma unroll
      for (int r = 0; r < 4; ++r)
        sv[ni][r] = kmv ? sa[ni][r] * scale : -1e9f;
    }
    // online softmax, per C-row (quad*4+r); reduce over ni regs + 16 lanes (l16)
#pragma unroll
    for (int r = 0; r < 4; ++r) {
      float rmax = sv[0][r];
#pragma unroll
      for (int ni = 1; ni < 8; ++ni) rmax = fmaxf(rmax, sv[ni][r]);
#pragma unroll
      for (int o = 1; o < 16; o <<= 1) rmax = fmaxf(rmax, __shfl_xor(rmax, o, 64));
      float newm = fmaxf(m_[r], rmax);
      float alpha = __expf(m_[r] - newm);
      float psum = 0.f;
#pragma unroll
      for (int ni = 0; ni < 8; ++ni) {
        float p = __expf(sv[ni][r] - newm);
        sv[ni][r] = p; psum += p;
      }
#pragma unroll
      for (int o = 1; o < 16; o <<= 1) psum += __shfl_xor(psum, o, 64);
      l_[r] = l_[r] * alpha + psum;
      m_[r] = newm;
#pragma unroll
      for (int ni = 0; ni < 4; ++ni) acc_o[ni][r] *= alpha;
    }
    // P -> LDS in [tok-chunk][q][32] layout (B-operand layout for PV)
#pragma unroll
    for (int ni = 0; ni < 8; ++ni) {
      int j = ni * 16 + l16;
      short* pp = &Ps[(j >> 5) * 2048 + (w * 16 + quad * 4) * 32 + (j & 31)];
#pragma unroll
      for (int r = 0; r < 4; ++r) pp[r * 32] = bfbits(sv[ni][r]);
    }
    __syncthreads();
    // PV: C[q][d] += P[q][t] * Vt[d][t]
#pragma unroll
    for (int kcp = 0; kcp < 4; ++kcp) {
      short8 af = *(const short8*)&Ps[kcp * 2048 + (w * 16 + l16) * 32 + quad * 8];
#pragma unroll
      for (int ni = 0; ni < 4; ++ni) {
        short8 bfrag = *(const short8*)&Vs[kcp * 2048 + (ni * 16 + l16) * 32 + quad * 8];
        acc_o[ni] = __builtin_amdgcn_mfma_f32_16x16x32_bf16(af, bfrag, acc_o[ni], 0, 0, 0);
      }
    }
  }
  // epilogue: scale by 1/l, write O into Q slot
  float linv[4];
#pragma unroll
  for (int r = 0; r < 4; ++r) linv[r] = 1.0f / l_[r];
#pragma unroll
  for (int ni = 0; ni < 4; ++ni)
#pragma unroll
    for (int r = 0; r < 4; ++r) {
      long row = (b << 9) + (qt << 6) + (w << 4) + quad * 4 + r;
      Og[row * 512 + h * 64 + ni * 16 + l16] = __float2bfloat16(acc_o[ni][r] * linv[r]);
    }
}

// ---------------- fused dual LN: y = LN(x + r) * g + b, 2 independent streams ----------------
__global__ __launch_bounds__(256) void k_ln2(
    const float* x0, const float* r0, const float* g0, const float* b0,
    float* yf0, bf16* yb0,
    const float* x1, const float* r1, const float* g1, const float* b1,
    float* yf1, bf16* yb1)
{
  int sel = blockIdx.x >> 12;
  long row = blockIdx.x & 4095;
  const float* x = sel ? x1 : x0;
  const float* r = sel ? r1 : r0;
  const float* g = sel ? g1 : g0;
  const float* bb = sel ? b1 : b0;
  float* yf = sel ? yf1 : yf0;
  bf16* yb = sel ? yb1 : yb0;
  int t = threadIdx.x;
  const float* xr = x + row * D_;
  const float* rr = r + row * D_;
  float v0 = xr[t] + rr[t];
  float v1 = xr[t + 256] + rr[t + 256];
  float s = v0 + v1;
  float ss = v0 * v0 + v1 * v1;
#pragma unroll
  for (int o = 32; o > 0; o >>= 1) {
    s += __shfl_down(s, o, 64);
    ss += __shfl_down(ss, o, 64);
  }
  __shared__ float rs[4];
  __shared__ float rss[4];
  int lane = t & 63, wid = t >> 6;
  if (lane == 0) { rs[wid] = s; rss[wid] = ss; }
  __syncthreads();
  s = rs[0] + rs[1] + rs[2] + rs[3];
  ss = rss[0] + rss[1] + rss[2] + rss[3];
  float mean = s * (1.0f / D_);
  float var = ss * (1.0f / D_) - mean * mean;
  float rstd = rsqrtf(var + 1e-5f);
  float o0 = (v0 - mean) * rstd * g[t]       + bb[t];
  float o1 = (v1 - mean) * rstd * g[t + 256] + bb[t + 256];
  if (yf) { float* yr = yf + row * D_; yr[t] = o0; yr[t + 256] = o1; }
  if (yb) { bf16* yr = yb + row * D_; yr[t] = __float2bfloat16(o0); yr[t + 256] = __float2bfloat16(o1); }
}

// ---------------- wave-per-row cross-masked softmax (final pooling) ----------------
__global__ __launch_bounds__(256) void k_softmax_x(float* __restrict__ S,
                                                   const int* __restrict__ vm,
                                                   const int* __restrict__ qm)
{
  int wrow = blockIdx.x * 4 + (threadIdx.x >> 6);
  int lane = threadIdx.x & 63;
  int b = wrow >> 9, i = wrow & 511;
  bool rowpad = (vm[(b << 9) + i] == 0);
  float* p = S + (long)wrow * 512;
  const int* qb = qm + (b << 9);
  int j0 = lane * 8;
  float4 a0 = *(const float4*)(p + j0);
  float4 a1 = *(const float4*)(p + j0 + 4);
  int4 m0 = *(const int4*)(qb + j0);
  int4 m1 = *(const int4*)(qb + j0 + 4);
  float v[8];
  v[0] = (rowpad || !m0.x) ? -1e9f : a0.x; v[1] = (rowpad || !m0.y) ? -1e9f : a0.y;
  v[2] = (rowpad || !m0.z) ? -1e9f : a0.z; v[3] = (rowpad || !m0.w) ? -1e9f : a0.w;
  v[4] = (rowpad || !m1.x) ? -1e9f : a1.x; v[5] = (rowpad || !m1.y) ? -1e9f : a1.y;
  v[6] = (rowpad || !m1.z) ? -1e9f : a1.z; v[7] = (rowpad || !m1.w) ? -1e9f : a1.w;
  float mx = v[0];
#pragma unroll
  for (int u = 1; u < 8; ++u) mx = fmaxf(mx, v[u]);
#pragma unroll
  for (int o = 1; o < 64; o <<= 1) mx = fmaxf(mx, __shfl_xor(mx, o, 64));
  float e[8], sum = 0.f;
#pragma unroll
  for (int u = 0; u < 8; ++u) { e[u] = __expf(v[u] - mx); sum += e[u]; }
#pragma unroll
  for (int o = 1; o < 64; o <<= 1) sum += __shfl_xor(sum, o, 64);
  float inv = 1.0f / sum;
  bf16 ob[8];
#pragma unroll
  for (int u = 0; u < 8; ++u) ob[u] = __float2bfloat16(e[u] * inv);
  bf16* pb = (bf16*)p;
  *(short8*)&pb[j0] = *(const short8*)ob;
}

// ---------------- final prep: Vw = bf16(V*w); Qt = bf16(Q^T) per batch ----------------
__global__ __launch_bounds__(256) void k_vwqt(const float* __restrict__ V,
                                              const float* __restrict__ Q,
                                              const float* __restrict__ w,
                                              bf16* __restrict__ Vw, bf16* __restrict__ Qt)
{
  __shared__ float Ls[32][33];
  int bx = blockIdx.x, t = threadIdx.x;
  if (bx < 2048) {
    int i = bx * 1024 + t * 4;
    float4 v = *(const float4*)(V + i);
    int k = i & 511;
    bf16 o[4] = { __float2bfloat16(v.x * w[k]),     __float2bfloat16(v.y * w[k + 1]),
                  __float2bfloat16(v.z * w[k + 2]), __float2bfloat16(v.w * w[k + 3]) };
    *(short4v*)&Vw[i] = *(const short4v*)o;
  } else {
    int q = bx - 2048; int b = q >> 8; int tq = q & 255;
    int tr = tq >> 4, tc = tq & 15;
    const float* Qb = Q + (long)b * 262144;
    bf16* Qtb = Qt + (long)b * 262144;
#pragma unroll
    for (int p = 0; p < 4; ++p) {
      int idx = t + p * 256; int lr = idx >> 5, lc = idx & 31;
      Ls[lr][lc] = Qb[(long)(tr * 32 + lr) * 512 + tc * 32 + lc];
    }
    __syncthreads();
#pragma unroll
    for (int p = 0; p < 4; ++p) {
      int idx = t + p * 256; int lr = idx >> 5, lc = idx & 31;
      Qtb[(long)(tc * 32 + lr) * 512 + tr * 32 + lc] = __float2bfloat16(Ls[lc][lr]);
    }
  }
}

// ---------------- out[b,k] = (1/512) * sum_i V[b,i,k] * T[b,i,k] ----------------
__global__ __launch_bounds__(256) void k_final_out(
    const float* __restrict__ V, const float* __restrict__ QT, float* __restrict__ out)
{
  int b = blockIdx.x >> 1;
  int k = ((blockIdx.x & 1) << 8) + threadIdx.x;
  const float* Vb = V + (long)b * N_ * D_ + k;
  const float* Tb = QT + (long)b * N_ * D_ + k;
  float acc = 0.0f;
  for (int i = 0; i < N_; ++i) acc += Vb[(long)i * D_] * Tb[(long)i * D_];
  out[b * D_ + k] = acc * (1.0f / 512.0f);
}

extern "C" void kernel_launch(void* const* d_in, const int* in_sizes, int n_in,
                              void* d_out, int out_size, void* d_ws, size_t ws_size,
                              hipStream_t stream)
{
  const float* in_v   = (const float*)d_in[0];
  const float* in_q   = (const float*)d_in[1];
  const int*   v_mask = (const int*)  d_in[2];
  const int*   q_mask = (const int*)  d_in[3];
  const float* aw  = (const float*)d_in[4];
  const float* ab  = (const float*)d_in[5];
  const float* awo = (const float*)d_in[6];
  const float* abo = (const float*)d_in[7];
  const float* lg  = (const float*)d_in[8];
  const float* lb  = (const float*)d_in[9];
  const float* fw1 = (const float*)d_in[10];
  const float* fb1 = (const float*)d_in[11];
  const float* fw2 = (const float*)d_in[12];
  const float* fb2 = (const float*)d_in[13];
  const float* atw = (const float*)d_in[14];
  const float* atb = (const float*)d_in[15];
  float* out = (float*)d_out;
  (void)atb;  // softmax is shift-invariant

  const int SZ = B_ * N_ * D_;
  char* wsb = (char*)d_ws;
  const long MB = 1024L * 1024;
  // 0 Vcur(8) | 8 Qcur(8) | 16 T(8) | 24 WT(16) | 40 Vcur_b(4) | 44 Qcur_b(4) |
  // 48 VA_b(4) | 52 QA_b(4) | 56 VQ_b(4) | 60 QKV s0(12) | 72 QKV s1(12) |
  // 84 Hid 2x16 (32) | 116 T2(8) | 124 Sf(8) | 132 Vw_b(4) | 136 Qt_b(4) -> 140 MB
  float* Vcur   = (float*)(wsb + 0 * MB);
  float* Qcur   = (float*)(wsb + 8 * MB);
  float* T      = (float*)(wsb + 16 * MB);
  bf16*  WT     = (bf16*) (wsb + 24 * MB);
  bf16*  Vcur_b = (bf16*) (wsb + 40 * MB);
  bf16*  Qcur_b = (bf16*) (wsb + 44 * MB);
  bf16*  VA_b   = (bf16*) (wsb + 48 * MB);
  bf16*  QA_b   = (bf16*) (wsb + 52 * MB);
  bf16*  VQ_b   = (bf16*) (wsb + 56 * MB);
  bf16*  QKV0   = (bf16*) (wsb + 60 * MB);
  bf16*  Hid    = (bf16*) (wsb + 84 * MB);
  float* T2     = (float*)(wsb + 116 * MB);
  float* Sf     = (float*)(wsb + 124 * MB);
  bf16*  Vw_b   = (bf16*) (wsb + 132 * MB);
  bf16*  Qt_b   = (bf16*) (wsb + 136 * MB);

  const long ZBIG = 1000000;
  const long TSTR = (long)(T2 - T);      // fp32 stream stride T -> T2

  k_prep<<<8192, 256, 0, stream>>>(in_v, Vcur, Vcur_b, SZ);
  k_prep<<<8192, 256, 0, stream>>>(in_q, Qcur, Qcur_b, SZ);

  for (int l = 0; l < L_; ++l) {
    const float* lgl = lg + (long)l * 6 * D_;
    const float* lbl = lb + (long)l * 6 * D_;
    k_wt<<<8192, 256, 0, stream>>>(aw + (long)l * 12 * 262144,
                                   awo + (long)l * 4 * 262144,
                                   fw1 + (long)l * 2 * 1048576,
                                   fw2 + (long)l * 2 * 1048576, WT);
    // ---- self-attention (2 streams batched: s0=v, s1=q) ----
    k_mfma<128><<<dim3(12, 32, 2), 256, 0, stream>>>(
        Vcur_b, Vcur_b, 2097152, 0, 0, 512,
        WT, 1048576, 0, 0, 512,
        ab + (long)l * 4 * 1536, 1536, 1.f, 0,
        nullptr, 0, 0, 0, 0, QKV0, 6291456, 0, 0, 0,
        512, 1, 1, 1);
    k_flash<<<dim3(8, 64, 2), 256, 0, stream>>>(QKV0, 6291456, v_mask, q_mask, 0.125f);
    k_mfma<128><<<dim3(4, 32, 2), 256, 0, stream>>>(
        QKV0, QKV0, 6291456, 0, 0, 512,
        WT + 3 * 262144, 1048576, 0, 0, 512,
        abo + (long)l * 4 * 512, 512, 1.f, 0,
        T, TSTR, 0, 0, 512, nullptr, 0, 0, 0, 0,
        512, 1, 1, 0);
    k_ln2<<<8192, 256, 0, stream>>>(Vcur, T,  lgl + 0 * D_, lbl + 0 * D_, nullptr, VA_b,
                                    Qcur, T2, lgl + 1 * D_, lbl + 1 * D_, nullptr, QA_b);
    // ---- cross attention vq: xq=VA, xkv=QA ----
    k_mfma<128><<<dim3(12, 32, 1), 256, 0, stream>>>(
        VA_b, QA_b, 0, 0, 0, 512,
        WT + 2 * 1048576, 0, 0, 0, 512,
        ab + (long)(l * 4 + 2) * 1536, 0, 1.f, 0,
        nullptr, 0, 0, 0, 0, QKV0, 0, 0, 0, 0,
        512, 1, 1, 1);
    k_flash<<<dim3(8, 64, 1), 256, 0, stream>>>(QKV0, 0, q_mask, q_mask, 0.125f);
    k_mfma<128><<<dim3(4, 32, 1), 256, 0, stream>>>(
        QKV0, QKV0, 0, 0, 0, 512,
        WT + (2 * 4 + 3) * 262144, 0, 0, 0, 512,
        abo + (long)(l * 4 + 2) * 512, 0, 1.f, 0,
        T, 0, 0, 0, 512, VQ_b, 0, 0, 0, 512,
        512, 1, 1, 0);
    // ---- cross attention qv: xq=QA, xkv=VQ ----
    k_mfma<128><<<dim3(12, 32, 1), 256, 0, stream>>>(
        QA_b, VQ_b, 0, 0, 0, 512,
        WT + 3 * 1048576, 0, 0, 0, 512,
        ab + (long)(l * 4 + 3) * 1536, 0, 1.f, 0,
        nullptr, 0, 0, 0, 0, QKV0, 0, 0, 0, 0,
        512, 1, 1, 1);
    k_flash<<<dim3(8, 64, 1), 256, 0, stream>>>(QKV0, 0, v_mask, v_mask, 0.125f);
    k_mfma<128><<<dim3(4, 32, 1), 256, 0, stream>>>(
        QKV0, QKV0, 0, 0, 0, 512,
        WT + (3 * 4 + 3) * 262144, 0, 0, 0, 512,
        abo + (long)(l * 4 + 3) * 512, 0, 1.f, 0,
        T2, 0, 0, 0, 512, nullptr, 0, 0, 0, 0,
        512, 1, 1, 0);
    k_ln2<<<8192, 256, 0, stream>>>(Vcur, T,  lgl + 2 * D_, lbl + 2 * D_, Vcur, Vcur_b,
                                    Qcur, T2, lgl + 3 * D_, lbl + 3 * D_, Qcur, Qcur_b);
    // ---- FFN (2 streams batched) ----
    k_mfma<128><<<dim3(16, 32, 2), 256, 0, stream>>>(
        Vcur_b, Vcur_b, 2097152, 0, 0, 512,
        WT + 4194304, 1048576, 0, 0, 512,
        fb1 + (long)l * 2 * 2048, 2048, 1.f, 1,
        nullptr, 0, 0, 0, 0, Hid, 8388608, 0, 0, 2048,
        512, 1, 1, 0);
    k_mfma<128><<<dim3(4, 32, 2), 256, 0, stream>>>(
        Hid, Hid, 8388608, 0, 0, 2048,
        WT + 6291456, 1048576, 0, 0, 2048,
        fb2 + (long)l * 2 * 512, 512, 1.f, 0,
        T, TSTR, 0, 0, 512, nullptr, 0, 0, 0, 0,
        2048, 1, 1, 0);
    k_ln2<<<8192, 256, 0, stream>>>(Vcur, T,  lgl + 4 * D_, lbl + 4 * D_, Vcur, Vcur_b,
                                    Qcur, T2, lgl + 5 * D_, lbl + 5 * D_, Qcur, Qcur_b);
  }

  // ---- final bilinear attention pooling ----
  k_vwqt<<<4096, 256, 0, stream>>>(Vcur, Qcur, atw, Vw_b, Qt_b);
  k_mfma<128><<<dim3(4, 4, 8), 256, 0, stream>>>(          // scores = (V*w) @ Q^T
      Vw_b, Vw_b, 0, 262144, 0, 512, Qcur_b, 0, 262144, 0, 512,
      nullptr, 0, 1.f, 0,
      Sf, 0, 262144, 0, 512, nullptr, 0, 0, 0, 0,
      512, 1, ZBIG, 0);
  k_softmax_x<<<1024, 256, 0, stream>>>(Sf, v_mask, q_mask);
  k_mfma<128><<<dim3(4, 4, 8), 256, 0, stream>>>(          // T = P @ Q
      (const bf16*)Sf, (const bf16*)Sf, 0, 524288, 0, 1024, Qt_b, 0, 262144, 0, 512,
      nullptr, 0, 1.f, 0,
      T, 0, 262144, 0, 512, nullptr, 0, 0, 0, 0,
      512, 1, ZBIG, 0);
  k_final_out<<<16, 256, 0, stream>>>(Vcur, T, out);

  (void)in_sizes; (void)n_in; (void)out_size; (void)ws_size;
}

// Round 6
// 1506.967 us; speedup vs baseline: 5.3916x; 1.0423x over previous
//
#include <hip/hip_runtime.h>
#include <hip/hip_bf16.h>

typedef __hip_bfloat16 bf16;
typedef __attribute__((ext_vector_type(8))) short short8;
typedef __attribute__((ext_vector_type(4))) short short4v;
typedef __attribute__((ext_vector_type(4))) float f32x4;

#define AS1 __attribute__((address_space(1)))
#define AS3 __attribute__((address_space(3)))

#define B_  8
#define N_  512
#define D_  512
#define H_  8
#define DH_ 64
#define DF_ 2048
#define L_  4

static __device__ __forceinline__ short bfbits(float x) {
  bf16 t = __float2bfloat16(x);
  return *reinterpret_cast<short*>(&t);
}

// ---------------- input prep: fp32 copy + bf16 shadow ----------------
__global__ __launch_bounds__(256) void k_prep(const float* __restrict__ in,
                                              float* __restrict__ f,
                                              bf16* __restrict__ b, int n) {
  int i = blockIdx.x * 256 + threadIdx.x;
  if (i < n) { float v = in[i]; f[i] = v; b[i] = __float2bfloat16(v); }
}

// ---------------- per-layer weight transpose + cast ----------------
__global__ __launch_bounds__(256) void k_wt(const float* __restrict__ aw_l,
                                            const float* __restrict__ awo_l,
                                            const float* __restrict__ fw1_l,
                                            const float* __restrict__ fw2_l,
                                            bf16* __restrict__ WT)
{
  __shared__ float Ls[32][33];
  int bx = blockIdx.x;
  const float* src; bf16* dst; int R, C, tr, tc;
  if (bx < 4096) {
    int id = bx >> 8, t = bx & 255;
    int m = id >> 2, part = id & 3;
    src = (part < 3) ? (aw_l + ((long)m * 3 + part) * D_ * D_)
                     : (awo_l + (long)m * D_ * D_);
    dst = WT + (long)id * 262144; R = 512; C = 512; tr = t >> 4; tc = t & 15;
  } else if (bx < 6144) {
    int q = bx - 4096; int id = q >> 10; int t = q & 1023;
    src = fw1_l + (long)id * D_ * DF_; dst = WT + 4194304 + (long)id * 1048576;
    R = 512; C = 2048; tr = t >> 6; tc = t & 63;
  } else {
    int q = bx - 6144; int id = q >> 10; int t = q & 1023;
    src = fw2_l + (long)id * DF_ * D_; dst = WT + 6291456 + (long)id * 1048576;
    R = 2048; C = 512; tr = t >> 4; tc = t & 15;
  }
  int tt = threadIdx.x;
#pragma unroll
  for (int p = 0; p < 4; ++p) {
    int idx = tt + p * 256; int lr = idx >> 5, lc = idx & 31;
    Ls[lr][lc] = src[(long)(tr * 32 + lr) * C + tc * 32 + lc];
  }
  __syncthreads();
#pragma unroll
  for (int p = 0; p < 4; ++p) {
    int idx = tt + p * 256; int lr = idx >> 5, lc = idx & 31;
    dst[(long)(tc * 32 + lr) * R + tr * 32 + lc] = __float2bfloat16(Ls[lc][lr]);
  }
}

// ---------------- MFMA GEMM (m97 structure). C = A @ B^T, both [rows][K-contig] bf16.
// mode 1 = fused QKV routing. kSplit>1: K split; partial kk -> Cf + kk*pStride,
// bias applied only in kk==0 partial (split users have scale=1, relu=0, Cb=null).
template<int BN>
__global__ __launch_bounds__(256, 2) void k_mfma(
    const bf16* __restrict__ A, const bf16* __restrict__ A2,
    long aS, long aB, long aH, int lda,
    const bf16* __restrict__ Bm, long bS, long bB, long bH, int ldb,
    const float* __restrict__ bias, long biasS, float scale, int relu,
    float* __restrict__ Cf, long cfS, long cfB, long cfH, int ldcf,
    bf16* __restrict__ Cb, long cbS, long cbB, long cbH, int ldcb,
    int kLen, int Hh, int zPerS, int mode, int kSplit, long pStride)
{
  constexpr int MI = (BN == 128) ? 4 : 2;
  constexpr int NI = 4;
  __shared__ short As[128 * 32];
  __shared__ short Bs[BN * 32];
  int tid = threadIdx.x;
  int w = tid >> 6, lane = tid & 63;
  int z = blockIdx.z;
  int kk = 0;
  if (kSplit > 1) { kk = z % kSplit; z /= kSplit; }
  int s = z / zPerS; int zz = z - s * zPerS;
  int zb = zz / Hh, zh = zz - zb * Hh;
  int row0 = blockIdx.y * 128;
  int col0 = blockIdx.x * BN;
  const bf16* Asel = (mode == 1 && col0 >= 512) ? A2 : A;
  const bf16* Ab = Asel + s * aS + zb * aB + zh * aH + (long)kk * kLen;
  const bf16* Bb = Bm + s * bS + zb * bB + zh * bH + (long)kk * kLen;
  int rw = (BN == 128) ? ((w >> 1) * 64) : (w * 32);
  int cw = (BN == 128) ? ((w & 1) * 64) : 0;
  int quad = lane >> 4, l16 = lane & 15;

  f32x4 acc[MI][NI];
#pragma unroll
  for (int i = 0; i < MI; ++i)
#pragma unroll
    for (int j = 0; j < NI; ++j) acc[i][j] = {0.f, 0.f, 0.f, 0.f};

  for (int k0 = 0; k0 < kLen; k0 += 32) {
#pragma unroll
    for (int i = 0; i < 2; ++i) {
      int o = i * 4096 + w * 1024 + lane * 16;
      int r = o >> 6;
      const bf16* g = Ab + (long)(row0 + r) * lda + k0 + ((o & 63) >> 1);
      char* lp = (char*)As + i * 4096 + w * 1024;
      __builtin_amdgcn_global_load_lds((const AS1 void*)g, (AS3 void*)lp, 16, 0, 0);
    }
    constexpr int BI = (BN == 128) ? 2 : 1;
#pragma unroll
    for (int i = 0; i < BI; ++i) {
      int o = i * 4096 + w * 1024 + lane * 16;
      int r = o >> 6;
      const bf16* g = Bb + (long)(col0 + r) * ldb + k0 + ((o & 63) >> 1);
      char* lp = (char*)Bs + i * 4096 + w * 1024;
      __builtin_amdgcn_global_load_lds((const AS1 void*)g, (AS3 void*)lp, 16, 0, 0);
    }
    __syncthreads();
    short8 af[MI], bfr[NI];
#pragma unroll
    for (int mi = 0; mi < MI; ++mi)
      af[mi] = *(const short8*)&As[(rw + mi * 16 + l16) * 32 + quad * 8];
#pragma unroll
    for (int ni = 0; ni < NI; ++ni)
      bfr[ni] = *(const short8*)&Bs[(cw + ni * 16 + l16) * 32 + quad * 8];
#pragma unroll
    for (int mi = 0; mi < MI; ++mi)
#pragma unroll
      for (int ni = 0; ni < NI; ++ni)
        acc[mi][ni] = __builtin_amdgcn_mfma_f32_16x16x32_bf16(af[mi], bfr[ni], acc[mi][ni], 0, 0, 0);
    __syncthreads();
  }

  const float* bp = (bias && kk == 0) ? bias + s * biasS : nullptr;
#pragma unroll
  for (int mi = 0; mi < MI; ++mi)
#pragma unroll
    for (int ni = 0; ni < NI; ++ni) {
      int cg = col0 + cw + ni * 16 + l16;
      float bv = bp ? bp[cg] : 0.0f;
#pragma unroll
      for (int r = 0; r < 4; ++r) {
        int rg = row0 + rw + mi * 16 + quad * 4 + r;
        float v = acc[mi][ni][r] * scale + bv;
        if (relu) v = fmaxf(v, 0.0f);
        if (mode == 1) {
          bf16* base = Cb + s * cbS;
          if (cg < 512) base[(long)rg * 512 + cg] = __float2bfloat16(v);
          else if (cg < 1024) base[2097152 + (long)rg * 512 + (cg - 512)] = __float2bfloat16(v);
          else {
            int c2 = cg - 1024;
            base[4194304 + ((long)((rg >> 9) * 8 + (c2 >> 6)) * 64 + (c2 & 63)) * 512 + (rg & 511)]
                = __float2bfloat16(v);
          }
        } else {
          if (Cf) Cf[s * cfS + (long)kk * pStride + zb * cfB + zh * cfH + (long)rg * ldcf + cg] = v;
          if (Cb) Cb[s * cbS + zb * cbB + zh * cbH + (long)rg * ldcb + cg] = __float2bfloat16(v);
        }
      }
    }
}

// ---------------- flash attention (unchanged from round 5) ----------------
__global__ __launch_bounds__(256, 2) void k_flash(
    const bf16* __restrict__ QKV, long sStride,
    const int* __restrict__ km0, const int* __restrict__ km1, float scale)
{
  __shared__ short Ks[2 * 128 * 32];
  __shared__ short Vs[4 * 64 * 32];
  __shared__ short Ps[4 * 64 * 32];
  int tid = threadIdx.x, w = tid >> 6, lane = tid & 63;
  int quad = lane >> 4, l16 = lane & 15;
  int s = blockIdx.z;
  const bf16* base = QKV + s * sStride;
  int bh = blockIdx.y, b = bh >> 3, h = bh & 7;
  int qt = blockIdx.x;
  const int* km = (s ? km1 : km0) + (b << 9);
  const bf16* Kg = base + 2097152;
  const bf16* Vt = base + 4194304;
  bf16* Og = (bf16*)base;

  int qrow = (b << 9) + (qt << 6) + (w << 4) + l16;
  short8 qf[2];
  qf[0] = *(const short8*)&base[(long)qrow * 512 + h * 64 + quad * 8];
  qf[1] = *(const short8*)&base[(long)qrow * 512 + h * 64 + 32 + quad * 8];

  float m_[4], l_[4];
  f32x4 acc_o[4];
#pragma unroll
  for (int r = 0; r < 4; ++r) { m_[r] = -3e38f; l_[r] = 0.f; }
#pragma unroll
  for (int ni = 0; ni < 4; ++ni) acc_o[ni] = {0.f, 0.f, 0.f, 0.f};

  for (int kt = 0; kt < 4; ++kt) {
    __syncthreads();
#pragma unroll
    for (int i = 0; i < 4; ++i) {
      int o = i * 4096 + w * 1024 + lane * 16;
      int kc = o >> 13, rem = o & 8191;
      int n = rem >> 6, cb = rem & 63;
      const bf16* g = Kg + ((long)((b << 9) + kt * 128 + n) << 9) + h * 64 + kc * 32 + (cb >> 1);
      char* lp = (char*)Ks + i * 4096 + w * 1024;
      __builtin_amdgcn_global_load_lds((const AS1 void*)g, (AS3 void*)lp, 16, 0, 0);
    }
#pragma unroll
    for (int i = 0; i < 4; ++i) {
      int o = i * 4096 + w * 1024 + lane * 16;
      int kc = o >> 12, rem = o & 4095;
      int d = rem >> 6, cb = rem & 63;
      const bf16* g = Vt + ((long)((bh << 6) + d) << 9) + kt * 128 + kc * 32 + (cb >> 1);
      char* lp = (char*)Vs + i * 4096 + w * 1024;
      __builtin_amdgcn_global_load_lds((const AS1 void*)g, (AS3 void*)lp, 16, 0, 0);
    }
    __syncthreads();
    f32x4 sa[8];
#pragma unroll
    for (int ni = 0; ni < 8; ++ni) sa[ni] = {0.f, 0.f, 0.f, 0.f};
#pragma unroll
    for (int kc = 0; kc < 2; ++kc)
#pragma unroll
      for (int ni = 0; ni < 8; ++ni) {
        short8 bfrag = *(const short8*)&Ks[kc * 4096 + (ni * 16 + l16) * 32 + quad * 8];
        sa[ni] = __builtin_amdgcn_mfma_f32_16x16x32_bf16(qf[kc], bfrag, sa[ni], 0, 0, 0);
      }
    float sv[8][4];
#pragma unroll
    for (int ni = 0; ni < 8; ++ni) {
      int kmv = km[kt * 128 + ni * 16 + l16];
#pragma unroll
      for (int r = 0; r < 4; ++r)
        sv[ni][r] = kmv ? sa[ni][r] * scale : -1e9f;
    }
#pragma unroll
    for (int r = 0; r < 4; ++r) {
      float rmax = sv[0][r];
#pragma unroll
      for (int ni = 1; ni < 8; ++ni) rmax = fmaxf(rmax, sv[ni][r]);
#pragma unroll
      for (int o = 1; o < 16; o <<= 1) rmax = fmaxf(rmax, __shfl_xor(rmax, o, 64));
      float newm = fmaxf(m_[r], rmax);
      float alpha = __expf(m_[r] - newm);
      float psum = 0.f;
#pragma unroll
      for (int ni = 0; ni < 8; ++ni) {
        float p = __expf(sv[ni][r] - newm);
        sv[ni][r] = p; psum += p;
      }
#pragma unroll
      for (int o = 1; o < 16; o <<= 1) psum += __shfl_xor(psum, o, 64);
      l_[r] = l_[r] * alpha + psum;
      m_[r] = newm;
#pragma unroll
      for (int ni = 0; ni < 4; ++ni) acc_o[ni][r] *= alpha;
    }
#pragma unroll
    for (int ni = 0; ni < 8; ++ni) {
      int j = ni * 16 + l16;
      short* pp = &Ps[(j >> 5) * 2048 + (w * 16 + quad * 4) * 32 + (j & 31)];
#pragma unroll
      for (int r = 0; r < 4; ++r) pp[r * 32] = bfbits(sv[ni][r]);
    }
    __syncthreads();
#pragma unroll
    for (int kcp = 0; kcp < 4; ++kcp) {
      short8 af = *(const short8*)&Ps[kcp * 2048 + (w * 16 + l16) * 32 + quad * 8];
#pragma unroll
      for (int ni = 0; ni < 4; ++ni) {
        short8 bfrag = *(const short8*)&Vs[kcp * 2048 + (ni * 16 + l16) * 32 + quad * 8];
        acc_o[ni] = __builtin_amdgcn_mfma_f32_16x16x32_bf16(af, bfrag, acc_o[ni], 0, 0, 0);
      }
    }
  }
  float linv[4];
#pragma unroll
  for (int r = 0; r < 4; ++r) linv[r] = 1.0f / l_[r];
#pragma unroll
  for (int ni = 0; ni < 4; ++ni)
#pragma unroll
    for (int r = 0; r < 4; ++r) {
      long row = (b << 9) + (qt << 6) + (w << 4) + quad * 4 + r;
      Og[row * 512 + h * 64 + ni * 16 + l16] = __float2bfloat16(acc_o[ni][r] * linv[r]);
    }
}

// ---------------- fused dual LN over two split-K partials:
// stream sel: y = LN(x + P[sel*2] + P[sel*2+1]) * g + b
__global__ __launch_bounds__(256) void k_ln2(
    const float* x0, const float* g0, const float* b0, float* yf0, bf16* yb0,
    const float* x1, const float* g1, const float* b1, float* yf1, bf16* yb1,
    const float* __restrict__ P, long pstr)
{
  int sel = blockIdx.x >> 12;
  long row = blockIdx.x & 4095;
  const float* x = sel ? x1 : x0;
  const float* g = sel ? g1 : g0;
  const float* bb = sel ? b1 : b0;
  float* yf = sel ? yf1 : yf0;
  bf16* yb = sel ? yb1 : yb0;
  int t = threadIdx.x;
  const float* xr = x + row * D_;
  const float* ra = P + (sel ? 2 : 0) * pstr + row * D_;
  const float* rb = ra + pstr;
  float v0 = xr[t] + ra[t] + rb[t];
  float v1 = xr[t + 256] + ra[t + 256] + rb[t + 256];
  float s = v0 + v1;
  float ss = v0 * v0 + v1 * v1;
#pragma unroll
  for (int o = 32; o > 0; o >>= 1) {
    s += __shfl_down(s, o, 64);
    ss += __shfl_down(ss, o, 64);
  }
  __shared__ float rs[4];
  __shared__ float rss[4];
  int lane = t & 63, wid = t >> 6;
  if (lane == 0) { rs[wid] = s; rss[wid] = ss; }
  __syncthreads();
  s = rs[0] + rs[1] + rs[2] + rs[3];
  ss = rss[0] + rss[1] + rss[2] + rss[3];
  float mean = s * (1.0f / D_);
  float var = ss * (1.0f / D_) - mean * mean;
  float rstd = rsqrtf(var + 1e-5f);
  float o0 = (v0 - mean) * rstd * g[t]       + bb[t];
  float o1 = (v1 - mean) * rstd * g[t + 256] + bb[t + 256];
  if (yf) { float* yr = yf + row * D_; yr[t] = o0; yr[t + 256] = o1; }
  if (yb) { bf16* yr = yb + row * D_; yr[t] = __float2bfloat16(o0); yr[t + 256] = __float2bfloat16(o1); }
}

// ---------------- sum two fp32 partials -> bf16 ----------------
__global__ __launch_bounds__(256) void k_sum2bf(const float* __restrict__ a,
                                                const float* __restrict__ b,
                                                bf16* __restrict__ o)
{
  int i = (blockIdx.x * 256 + threadIdx.x) * 4;
  float4 va = *(const float4*)(a + i);
  float4 vb = *(const float4*)(b + i);
  bf16 ov[4] = { __float2bfloat16(va.x + vb.x), __float2bfloat16(va.y + vb.y),
                 __float2bfloat16(va.z + vb.z), __float2bfloat16(va.w + vb.w) };
  *(short4v*)&o[i] = *(const short4v*)ov;
}

// ---------------- wave-per-row cross-masked softmax (final pooling) ----------------
__global__ __launch_bounds__(256) void k_softmax_x(float* __restrict__ S,
                                                   const int* __restrict__ vm,
                                                   const int* __restrict__ qm)
{
  int wrow = blockIdx.x * 4 + (threadIdx.x >> 6);
  int lane = threadIdx.x & 63;
  int b = wrow >> 9, i = wrow & 511;
  bool rowpad = (vm[(b << 9) + i] == 0);
  float* p = S + (long)wrow * 512;
  const int* qb = qm + (b << 9);
  int j0 = lane * 8;
  float4 a0 = *(const float4*)(p + j0);
  float4 a1 = *(const float4*)(p + j0 + 4);
  int4 m0 = *(const int4*)(qb + j0);
  int4 m1 = *(const int4*)(qb + j0 + 4);
  float v[8];
  v[0] = (rowpad || !m0.x) ? -1e9f : a0.x; v[1] = (rowpad || !m0.y) ? -1e9f : a0.y;
  v[2] = (rowpad || !m0.z) ? -1e9f : a0.z; v[3] = (rowpad || !m0.w) ? -1e9f : a0.w;
  v[4] = (rowpad || !m1.x) ? -1e9f : a1.x; v[5] = (rowpad || !m1.y) ? -1e9f : a1.y;
  v[6] = (rowpad || !m1.z) ? -1e9f : a1.z; v[7] = (rowpad || !m1.w) ? -1e9f : a1.w;
  float mx = v[0];
#pragma unroll
  for (int u = 1; u < 8; ++u) mx = fmaxf(mx, v[u]);
#pragma unroll
  for (int o = 1; o < 64; o <<= 1) mx = fmaxf(mx, __shfl_xor(mx, o, 64));
  float e[8], sum = 0.f;
#pragma unroll
  for (int u = 0; u < 8; ++u) { e[u] = __expf(v[u] - mx); sum += e[u]; }
#pragma unroll
  for (int o = 1; o < 64; o <<= 1) sum += __shfl_xor(sum, o, 64);
  float inv = 1.0f / sum;
  bf16 ob[8];
#pragma unroll
  for (int u = 0; u < 8; ++u) ob[u] = __float2bfloat16(e[u] * inv);
  bf16* pb = (bf16*)p;
  *(short8*)&pb[j0] = *(const short8*)ob;
}

// ---------------- final prep: Vw = bf16(V*w); Qt = bf16(Q^T) per batch ----------------
__global__ __launch_bounds__(256) void k_vwqt(const float* __restrict__ V,
                                              const float* __restrict__ Q,
                                              const float* __restrict__ w,
                                              bf16* __restrict__ Vw, bf16* __restrict__ Qt)
{
  __shared__ float Ls[32][33];
  int bx = blockIdx.x, t = threadIdx.x;
  if (bx < 2048) {
    int i = bx * 1024 + t * 4;
    float4 v = *(const float4*)(V + i);
    int k = i & 511;
    bf16 o[4] = { __float2bfloat16(v.x * w[k]),     __float2bfloat16(v.y * w[k + 1]),
                  __float2bfloat16(v.z * w[k + 2]), __float2bfloat16(v.w * w[k + 3]) };
    *(short4v*)&Vw[i] = *(const short4v*)o;
  } else {
    int q = bx - 2048; int b = q >> 8; int tq = q & 255;
    int tr = tq >> 4, tc = tq & 15;
    const float* Qb = Q + (long)b * 262144;
    bf16* Qtb = Qt + (long)b * 262144;
#pragma unroll
    for (int p = 0; p < 4; ++p) {
      int idx = t + p * 256; int lr = idx >> 5, lc = idx & 31;
      Ls[lr][lc] = Qb[(long)(tr * 32 + lr) * 512 + tc * 32 + lc];
    }
    __syncthreads();
#pragma unroll
    for (int p = 0; p < 4; ++p) {
      int idx = t + p * 256; int lr = idx >> 5, lc = idx & 31;
      Qtb[(long)(tc * 32 + lr) * 512 + tr * 32 + lc] = __float2bfloat16(Ls[lc][lr]);
    }
  }
}

// ---------------- out[b,k] = (1/512) * sum_i V[b,i,k] * T[b,i,k] ----------------
__global__ __launch_bounds__(256) void k_final_out(
    const float* __restrict__ V, const float* __restrict__ QT, float* __restrict__ out)
{
  int b = blockIdx.x >> 1;
  int k = ((blockIdx.x & 1) << 8) + threadIdx.x;
  const float* Vb = V + (long)b * N_ * D_ + k;
  const float* Tb = QT + (long)b * N_ * D_ + k;
  float acc = 0.0f;
  for (int i = 0; i < N_; ++i) acc += Vb[(long)i * D_] * Tb[(long)i * D_];
  out[b * D_ + k] = acc * (1.0f / 512.0f);
}

extern "C" void kernel_launch(void* const* d_in, const int* in_sizes, int n_in,
                              void* d_out, int out_size, void* d_ws, size_t ws_size,
                              hipStream_t stream)
{
  const float* in_v   = (const float*)d_in[0];
  const float* in_q   = (const float*)d_in[1];
  const int*   v_mask = (const int*)  d_in[2];
  const int*   q_mask = (const int*)  d_in[3];
  const float* aw  = (const float*)d_in[4];
  const float* ab  = (const float*)d_in[5];
  const float* awo = (const float*)d_in[6];
  const float* abo = (const float*)d_in[7];
  const float* lg  = (const float*)d_in[8];
  const float* lb  = (const float*)d_in[9];
  const float* fw1 = (const float*)d_in[10];
  const float* fb1 = (const float*)d_in[11];
  const float* fw2 = (const float*)d_in[12];
  const float* fb2 = (const float*)d_in[13];
  const float* atw = (const float*)d_in[14];
  const float* atb = (const float*)d_in[15];
  float* out = (float*)d_out;
  (void)atb;  // softmax is shift-invariant

  const int SZ = B_ * N_ * D_;
  char* wsb = (char*)d_ws;
  const long MB = 1024L * 1024;
  // 0 Vcur(8) | 8 Qcur(8) | 16 P0..P3 (4x8=32) | 48 WT(16) | 64 Vcur_b(4) |
  // 68 Qcur_b(4) | 72 VA_b(4) | 76 QA_b(4) | 80 VQ_b(4) | 84 QKV s0(12) |
  // 96 QKV s1(12) | 108 Hid(2x16=32) -> 140 MB.
  // Final pooling aliases: Sf=P0, Vw_b=P1[0:4], Qt_b=P1[4:8], Tfin=P2.
  float* Vcur   = (float*)(wsb + 0 * MB);
  float* Qcur   = (float*)(wsb + 8 * MB);
  float* P0     = (float*)(wsb + 16 * MB);
  const long PSZ = 2097152;               // floats per partial (8 MB)
  bf16*  WT     = (bf16*) (wsb + 48 * MB);
  bf16*  Vcur_b = (bf16*) (wsb + 64 * MB);
  bf16*  Qcur_b = (bf16*) (wsb + 68 * MB);
  bf16*  VA_b   = (bf16*) (wsb + 72 * MB);
  bf16*  QA_b   = (bf16*) (wsb + 76 * MB);
  bf16*  VQ_b   = (bf16*) (wsb + 80 * MB);
  bf16*  QKV0   = (bf16*) (wsb + 84 * MB);
  bf16*  Hid    = (bf16*) (wsb + 108 * MB);
  float* Sf     = P0;
  bf16*  Vw_b   = (bf16*) (wsb + 24 * MB);
  bf16*  Qt_b   = (bf16*) (wsb + 28 * MB);
  float* Tfin   = (float*)(wsb + 32 * MB);

  const long ZBIG = 1000000;

  k_prep<<<8192, 256, 0, stream>>>(in_v, Vcur, Vcur_b, SZ);
  k_prep<<<8192, 256, 0, stream>>>(in_q, Qcur, Qcur_b, SZ);

  for (int l = 0; l < L_; ++l) {
    const float* lgl = lg + (long)l * 6 * D_;
    const float* lbl = lb + (long)l * 6 * D_;
    k_wt<<<8192, 256, 0, stream>>>(aw + (long)l * 12 * 262144,
                                   awo + (long)l * 4 * 262144,
                                   fw1 + (long)l * 2 * 1048576,
                                   fw2 + (long)l * 2 * 1048576, WT);
    // ---- self-attention (2 streams: s0=v, s1=q) ----
    k_mfma<128><<<dim3(12, 32, 2), 256, 0, stream>>>(
        Vcur_b, Vcur_b, 2097152, 0, 0, 512,
        WT, 1048576, 0, 0, 512,
        ab + (long)l * 4 * 1536, 1536, 1.f, 0,
        nullptr, 0, 0, 0, 0, QKV0, 6291456, 0, 0, 0,
        512, 1, 1, 1, 1, 0);
    k_flash<<<dim3(8, 64, 2), 256, 0, stream>>>(QKV0, 6291456, v_mask, q_mask, 0.125f);
    k_mfma<128><<<dim3(4, 32, 4), 256, 0, stream>>>(      // out-proj, splitK=2 x 2 streams
        QKV0, QKV0, 6291456, 0, 0, 512,
        WT + 3 * 262144, 1048576, 0, 0, 512,
        abo + (long)l * 4 * 512, 512, 1.f, 0,
        P0, 2 * PSZ, 0, 0, 512, nullptr, 0, 0, 0, 0,
        256, 1, 1, 0, 2, PSZ);
    k_ln2<<<8192, 256, 0, stream>>>(Vcur, lgl + 0 * D_, lbl + 0 * D_, nullptr, VA_b,
                                    Qcur, lgl + 1 * D_, lbl + 1 * D_, nullptr, QA_b,
                                    P0, PSZ);
    // ---- cross attention vq: xq=VA, xkv=QA ----
    k_mfma<128><<<dim3(12, 32, 1), 256, 0, stream>>>(
        VA_b, QA_b, 0, 0, 0, 512,
        WT + 2 * 1048576, 0, 0, 0, 512,
        ab + (long)(l * 4 + 2) * 1536, 0, 1.f, 0,
        nullptr, 0, 0, 0, 0, QKV0, 0, 0, 0, 0,
        512, 1, 1, 1, 1, 0);
    k_flash<<<dim3(8, 64, 1), 256, 0, stream>>>(QKV0, 0, q_mask, q_mask, 0.125f);
    k_mfma<64><<<dim3(8, 32, 2), 256, 0, stream>>>(       // out-proj vq -> P0,P1
        QKV0, QKV0, 0, 0, 0, 512,
        WT + (2 * 4 + 3) * 262144, 0, 0, 0, 512,
        abo + (long)(l * 4 + 2) * 512, 0, 1.f, 0,
        P0, 0, 0, 0, 512, nullptr, 0, 0, 0, 0,
        256, 1, 1, 0, 2, PSZ);
    k_sum2bf<<<2048, 256, 0, stream>>>(P0, P0 + PSZ, VQ_b);
    // ---- cross attention qv: xq=QA, xkv=VQ ----
    k_mfma<128><<<dim3(12, 32, 1), 256, 0, stream>>>(
        QA_b, VQ_b, 0, 0, 0, 512,
        WT + 3 * 1048576, 0, 0, 0, 512,
        ab + (long)(l * 4 + 3) * 1536, 0, 1.f, 0,
        nullptr, 0, 0, 0, 0, QKV0, 0, 0, 0, 0,
        512, 1, 1, 1, 1, 0);
    k_flash<<<dim3(8, 64, 1), 256, 0, stream>>>(QKV0, 0, v_mask, v_mask, 0.125f);
    k_mfma<64><<<dim3(8, 32, 2), 256, 0, stream>>>(       // out-proj qv -> P2,P3
        QKV0, QKV0, 0, 0, 0, 512,
        WT + (3 * 4 + 3) * 262144, 0, 0, 0, 512,
        abo + (long)(l * 4 + 3) * 512, 0, 1.f, 0,
        P0 + 2 * PSZ, 0, 0, 0, 512, nullptr, 0, 0, 0, 0,
        256, 1, 1, 0, 2, PSZ);
    k_ln2<<<8192, 256, 0, stream>>>(Vcur, lgl + 2 * D_, lbl + 2 * D_, Vcur, Vcur_b,
                                    Qcur, lgl + 3 * D_, lbl + 3 * D_, Qcur, Qcur_b,
                                    P0, PSZ);
    // ---- FFN (2 streams) ----
    k_mfma<128><<<dim3(16, 32, 2), 256, 0, stream>>>(
        Vcur_b, Vcur_b, 2097152, 0, 0, 512,
        WT + 4194304, 1048576, 0, 0, 512,
        fb1 + (long)l * 2 * 2048, 2048, 1.f, 1,
        nullptr, 0, 0, 0, 0, Hid, 8388608, 0, 0, 2048,
        512, 1, 1, 0, 1, 0);
    k_mfma<128><<<dim3(4, 32, 4), 256, 0, stream>>>(      // fc2 splitK=2 x 2 streams
        Hid, Hid, 8388608, 0, 0, 2048,
        WT + 6291456, 1048576, 0, 0, 2048,
        fb2 + (long)l * 2 * 512, 512, 1.f, 0,
        P0, 2 * PSZ, 0, 0, 512, nullptr, 0, 0, 0, 0,
        1024, 1, 1, 0, 2, PSZ);
    k_ln2<<<8192, 256, 0, stream>>>(Vcur, lgl + 4 * D_, lbl + 4 * D_, Vcur, Vcur_b,
                                    Qcur, lgl + 5 * D_, lbl + 5 * D_, Qcur, Qcur_b,
                                    P0, PSZ);
  }

  // ---- final bilinear attention pooling ----
  k_vwqt<<<4096, 256, 0, stream>>>(Vcur, Qcur, atw, Vw_b, Qt_b);
  k_mfma<128><<<dim3(4, 4, 8), 256, 0, stream>>>(          // scores = (V*w) @ Q^T -> Sf(=P0)
      Vw_b, Vw_b, 0, 262144, 0, 512, Qcur_b, 0, 262144, 0, 512,
      nullptr, 0, 1.f, 0,
      Sf, 0, 262144, 0, 512, nullptr, 0, 0, 0, 0,
      512, 1, ZBIG, 0, 1, 0);
  k_softmax_x<<<1024, 256, 0, stream>>>(Sf, v_mask, q_mask);
  k_mfma<128><<<dim3(4, 4, 8), 256, 0, stream>>>(          // Tfin = P @ Q
      (const bf16*)Sf, (const bf16*)Sf, 0, 524288, 0, 1024, Qt_b, 0, 262144, 0, 512,
      nullptr, 0, 1.f, 0,
      Tfin, 0, 262144, 0, 512, nullptr, 0, 0, 0, 0,
      512, 1, ZBIG, 0, 1, 0);
  k_final_out<<<16, 256, 0, stream>>>(Vcur, Tfin, out);

  (void)in_sizes; (void)n_in; (void)out_size; (void)ws_size;
}

// Round 7
// 1457.841 us; speedup vs baseline: 5.5733x; 1.0337x over previous
//
#include <hip/hip_runtime.h>
#include <hip/hip_bf16.h>

typedef __hip_bfloat16 bf16;
typedef __attribute__((ext_vector_type(8))) short short8;
typedef __attribute__((ext_vector_type(4))) short short4v;
typedef __attribute__((ext_vector_type(4))) float f32x4;

#define AS1 __attribute__((address_space(1)))
#define AS3 __attribute__((address_space(3)))

#define B_  8
#define N_  512
#define D_  512
#define H_  8
#define DH_ 64
#define DF_ 2048
#define L_  4

static __device__ __forceinline__ short bfbits(float x) {
  bf16 t = __float2bfloat16(x);
  return *reinterpret_cast<short*>(&t);
}

// ---------------- input prep (both tensors in one dispatch) ----------------
__global__ __launch_bounds__(256) void k_prep2(const float* __restrict__ a,
                                               float* __restrict__ fa, bf16* __restrict__ ba,
                                               const float* __restrict__ bsrc,
                                               float* __restrict__ fb, bf16* __restrict__ bb,
                                               int n) {
  int i = blockIdx.x * 256 + threadIdx.x;
  if (i < n) { float v = a[i]; fa[i] = v; ba[i] = __float2bfloat16(v); }
  else { int j = i - n; float v = bsrc[j]; fb[j] = v; bb[j] = __float2bfloat16(v); }
}

// ---------------- per-layer weight transpose + cast ----------------
__global__ __launch_bounds__(256) void k_wt(const float* __restrict__ aw_l,
                                            const float* __restrict__ awo_l,
                                            const float* __restrict__ fw1_l,
                                            const float* __restrict__ fw2_l,
                                            bf16* __restrict__ WT)
{
  __shared__ float Ls[32][33];
  int bx = blockIdx.x;
  const float* src; bf16* dst; int R, C, tr, tc;
  if (bx < 4096) {
    int id = bx >> 8, t = bx & 255;
    int m = id >> 2, part = id & 3;
    src = (part < 3) ? (aw_l + ((long)m * 3 + part) * D_ * D_)
                     : (awo_l + (long)m * D_ * D_);
    dst = WT + (long)id * 262144; R = 512; C = 512; tr = t >> 4; tc = t & 15;
  } else if (bx < 6144) {
    int q = bx - 4096; int id = q >> 10; int t = q & 1023;
    src = fw1_l + (long)id * D_ * DF_; dst = WT + 4194304 + (long)id * 1048576;
    R = 512; C = 2048; tr = t >> 6; tc = t & 63;
  } else {
    int q = bx - 6144; int id = q >> 10; int t = q & 1023;
    src = fw2_l + (long)id * DF_ * D_; dst = WT + 6291456 + (long)id * 1048576;
    R = 2048; C = 512; tr = t >> 4; tc = t & 15;
  }
  int tt = threadIdx.x;
#pragma unroll
  for (int p = 0; p < 4; ++p) {
    int idx = tt + p * 256; int lr = idx >> 5, lc = idx & 31;
    Ls[lr][lc] = src[(long)(tr * 32 + lr) * C + tc * 32 + lc];
  }
  __syncthreads();
#pragma unroll
  for (int p = 0; p < 4; ++p) {
    int idx = tt + p * 256; int lr = idx >> 5, lc = idx & 31;
    dst[(long)(tc * 32 + lr) * R + tr * 32 + lc] = __float2bfloat16(Ls[lc][lr]);
  }
}

// ---------------- MFMA GEMM, BK=64 two-plane K-loop (one barrier pair / 2 K-steps).
// C = A @ B^T, both [rows][K-contig] bf16. mode 1 = fused QKV routing.
// kSplit>1: partial kk -> Cf + kk*pStride, bias only in kk==0.
template<int BN>
__global__ __launch_bounds__(256, 2) void k_mfma(
    const bf16* __restrict__ A, const bf16* __restrict__ A2,
    long aS, long aB, long aH, int lda,
    const bf16* __restrict__ Bm, long bS, long bB, long bH, int ldb,
    const float* __restrict__ bias, long biasS, float scale, int relu,
    float* __restrict__ Cf, long cfS, long cfB, long cfH, int ldcf,
    bf16* __restrict__ Cb, long cbS, long cbB, long cbH, int ldcb,
    int kLen, int Hh, int zPerS, int mode, int kSplit, long pStride)
{
  constexpr int MI = (BN == 128) ? 4 : 2;
  constexpr int NI = 4;
  __shared__ short As[2 * 128 * 32];       // two BK=32 planes, m97 layout each
  __shared__ short Bs[2 * BN * 32];
  int tid = threadIdx.x;
  int w = tid >> 6, lane = tid & 63;
  int z = blockIdx.z;
  int kk = 0;
  if (kSplit > 1) { kk = z % kSplit; z /= kSplit; }
  int s = z / zPerS; int zz = z - s * zPerS;
  int zb = zz / Hh, zh = zz - zb * Hh;
  int row0 = blockIdx.y * 128;
  int col0 = blockIdx.x * BN;
  const bf16* Asel = (mode == 1 && col0 >= 512) ? A2 : A;
  const bf16* Ab = Asel + s * aS + zb * aB + zh * aH + (long)kk * kLen;
  const bf16* Bb = Bm + s * bS + zb * bB + zh * bH + (long)kk * kLen;
  int rw = (BN == 128) ? ((w >> 1) * 64) : (w * 32);
  int cw = (BN == 128) ? ((w & 1) * 64) : 0;
  int quad = lane >> 4, l16 = lane & 15;

  f32x4 acc[MI][NI];
#pragma unroll
  for (int i = 0; i < MI; ++i)
#pragma unroll
    for (int j = 0; j < NI; ++j) acc[i][j] = {0.f, 0.f, 0.f, 0.f};

  for (int k0 = 0; k0 < kLen; k0 += 64) {
#pragma unroll
    for (int hf = 0; hf < 2; ++hf) {
#pragma unroll
      for (int i = 0; i < 2; ++i) {        // A plane hf: 8 KB
        int o = i * 4096 + w * 1024 + lane * 16;
        int r = o >> 6;
        const bf16* g = Ab + (long)(row0 + r) * lda + k0 + hf * 32 + ((o & 63) >> 1);
        char* lp = (char*)As + hf * 8192 + i * 4096 + w * 1024;
        __builtin_amdgcn_global_load_lds((const AS1 void*)g, (AS3 void*)lp, 16, 0, 0);
      }
      constexpr int BI = (BN == 128) ? 2 : 1;
#pragma unroll
      for (int i = 0; i < BI; ++i) {       // B plane hf
        int o = i * 4096 + w * 1024 + lane * 16;
        int r = o >> 6;
        const bf16* g = Bb + (long)(col0 + r) * ldb + k0 + hf * 32 + ((o & 63) >> 1);
        char* lp = (char*)Bs + hf * (BN * 64) + i * 4096 + w * 1024;
        __builtin_amdgcn_global_load_lds((const AS1 void*)g, (AS3 void*)lp, 16, 0, 0);
      }
    }
    __syncthreads();
#pragma unroll
    for (int hf = 0; hf < 2; ++hf) {
      short8 af[MI], bfr[NI];
#pragma unroll
      for (int mi = 0; mi < MI; ++mi)
        af[mi] = *(const short8*)&As[hf * 4096 + (rw + mi * 16 + l16) * 32 + quad * 8];
#pragma unroll
      for (int ni = 0; ni < NI; ++ni)
        bfr[ni] = *(const short8*)&Bs[hf * (BN * 32) + (cw + ni * 16 + l16) * 32 + quad * 8];
#pragma unroll
      for (int mi = 0; mi < MI; ++mi)
#pragma unroll
        for (int ni = 0; ni < NI; ++ni)
          acc[mi][ni] = __builtin_amdgcn_mfma_f32_16x16x32_bf16(af[mi], bfr[ni], acc[mi][ni], 0, 0, 0);
    }
    __syncthreads();
  }

  const float* bp = (bias && kk == 0) ? bias + s * biasS : nullptr;
#pragma unroll
  for (int mi = 0; mi < MI; ++mi)
#pragma unroll
    for (int ni = 0; ni < NI; ++ni) {
      int cg = col0 + cw + ni * 16 + l16;
      float bv = bp ? bp[cg] : 0.0f;
#pragma unroll
      for (int r = 0; r < 4; ++r) {
        int rg = row0 + rw + mi * 16 + quad * 4 + r;
        float v = acc[mi][ni][r] * scale + bv;
        if (relu) v = fmaxf(v, 0.0f);
        if (mode == 1) {
          bf16* base = Cb + s * cbS;
          if (cg < 512) base[(long)rg * 512 + cg] = __float2bfloat16(v);
          else if (cg < 1024) base[2097152 + (long)rg * 512 + (cg - 512)] = __float2bfloat16(v);
          else {
            int c2 = cg - 1024;
            base[4194304 + ((long)((rg >> 9) * 8 + (c2 >> 6)) * 64 + (c2 & 63)) * 512 + (rg & 511)]
                = __float2bfloat16(v);
          }
        } else {
          if (Cf) Cf[s * cfS + (long)kk * pStride + zb * cfB + zh * cfH + (long)rg * ldcf + cg] = v;
          if (Cb) Cb[s * cbS + zb * cbB + zh * cbH + (long)rg * ldcb + cg] = __float2bfloat16(v);
        }
      }
    }
}

// ---------------- flash attention (unchanged) ----------------
__global__ __launch_bounds__(256, 2) void k_flash(
    const bf16* __restrict__ QKV, long sStride,
    const int* __restrict__ km0, const int* __restrict__ km1, float scale)
{
  __shared__ short Ks[2 * 128 * 32];
  __shared__ short Vs[4 * 64 * 32];
  __shared__ short Ps[4 * 64 * 32];
  int tid = threadIdx.x, w = tid >> 6, lane = tid & 63;
  int quad = lane >> 4, l16 = lane & 15;
  int s = blockIdx.z;
  const bf16* base = QKV + s * sStride;
  int bh = blockIdx.y, b = bh >> 3, h = bh & 7;
  int qt = blockIdx.x;
  const int* km = (s ? km1 : km0) + (b << 9);
  const bf16* Kg = base + 2097152;
  const bf16* Vt = base + 4194304;
  bf16* Og = (bf16*)base;

  int qrow = (b << 9) + (qt << 6) + (w << 4) + l16;
  short8 qf[2];
  qf[0] = *(const short8*)&base[(long)qrow * 512 + h * 64 + quad * 8];
  qf[1] = *(const short8*)&base[(long)qrow * 512 + h * 64 + 32 + quad * 8];

  float m_[4], l_[4];
  f32x4 acc_o[4];
#pragma unroll
  for (int r = 0; r < 4; ++r) { m_[r] = -3e38f; l_[r] = 0.f; }
#pragma unroll
  for (int ni = 0; ni < 4; ++ni) acc_o[ni] = {0.f, 0.f, 0.f, 0.f};

  for (int kt = 0; kt < 4; ++kt) {
    __syncthreads();
#pragma unroll
    for (int i = 0; i < 4; ++i) {
      int o = i * 4096 + w * 1024 + lane * 16;
      int kc = o >> 13, rem = o & 8191;
      int n = rem >> 6, cb = rem & 63;
      const bf16* g = Kg + ((long)((b << 9) + kt * 128 + n) << 9) + h * 64 + kc * 32 + (cb >> 1);
      char* lp = (char*)Ks + i * 4096 + w * 1024;
      __builtin_amdgcn_global_load_lds((const AS1 void*)g, (AS3 void*)lp, 16, 0, 0);
    }
#pragma unroll
    for (int i = 0; i < 4; ++i) {
      int o = i * 4096 + w * 1024 + lane * 16;
      int kc = o >> 12, rem = o & 4095;
      int d = rem >> 6, cb = rem & 63;
      const bf16* g = Vt + ((long)((bh << 6) + d) << 9) + kt * 128 + kc * 32 + (cb >> 1);
      char* lp = (char*)Vs + i * 4096 + w * 1024;
      __builtin_amdgcn_global_load_lds((const AS1 void*)g, (AS3 void*)lp, 16, 0, 0);
    }
    __syncthreads();
    f32x4 sa[8];
#pragma unroll
    for (int ni = 0; ni < 8; ++ni) sa[ni] = {0.f, 0.f, 0.f, 0.f};
#pragma unroll
    for (int kc = 0; kc < 2; ++kc)
#pragma unroll
      for (int ni = 0; ni < 8; ++ni) {
        short8 bfrag = *(const short8*)&Ks[kc * 4096 + (ni * 16 + l16) * 32 + quad * 8];
        sa[ni] = __builtin_amdgcn_mfma_f32_16x16x32_bf16(qf[kc], bfrag, sa[ni], 0, 0, 0);
      }
    float sv[8][4];
#pragma unroll
    for (int ni = 0; ni < 8; ++ni) {
      int kmv = km[kt * 128 + ni * 16 + l16];
#pragma unroll
      for (int r = 0; r < 4; ++r)
        sv[ni][r] = kmv ? sa[ni][r] * scale : -1e9f;
    }
#pragma unroll
    for (int r = 0; r < 4; ++r) {
      float rmax = sv[0][r];
#pragma unroll
      for (int ni = 1; ni < 8; ++ni) rmax = fmaxf(rmax, sv[ni][r]);
#pragma unroll
      for (int o = 1; o < 16; o <<= 1) rmax = fmaxf(rmax, __shfl_xor(rmax, o, 64));
      float newm = fmaxf(m_[r], rmax);
      float alpha = __expf(m_[r] - newm);
      float psum = 0.f;
#pragma unroll
      for (int ni = 0; ni < 8; ++ni) {
        float p = __expf(sv[ni][r] - newm);
        sv[ni][r] = p; psum += p;
      }
#pragma unroll
      for (int o = 1; o < 16; o <<= 1) psum += __shfl_xor(psum, o, 64);
      l_[r] = l_[r] * alpha + psum;
      m_[r] = newm;
#pragma unroll
      for (int ni = 0; ni < 4; ++ni) acc_o[ni][r] *= alpha;
    }
#pragma unroll
    for (int ni = 0; ni < 8; ++ni) {
      int j = ni * 16 + l16;
      short* pp = &Ps[(j >> 5) * 2048 + (w * 16 + quad * 4) * 32 + (j & 31)];
#pragma unroll
      for (int r = 0; r < 4; ++r) pp[r * 32] = bfbits(sv[ni][r]);
    }
    __syncthreads();
#pragma unroll
    for (int kcp = 0; kcp < 4; ++kcp) {
      short8 af = *(const short8*)&Ps[kcp * 2048 + (w * 16 + l16) * 32 + quad * 8];
#pragma unroll
      for (int ni = 0; ni < 4; ++ni) {
        short8 bfrag = *(const short8*)&Vs[kcp * 2048 + (ni * 16 + l16) * 32 + quad * 8];
        acc_o[ni] = __builtin_amdgcn_mfma_f32_16x16x32_bf16(af, bfrag, acc_o[ni], 0, 0, 0);
      }
    }
  }
  float linv[4];
#pragma unroll
  for (int r = 0; r < 4; ++r) linv[r] = 1.0f / l_[r];
#pragma unroll
  for (int ni = 0; ni < 4; ++ni)
#pragma unroll
    for (int r = 0; r < 4; ++r) {
      long row = (b << 9) + (qt << 6) + (w << 4) + quad * 4 + r;
      Og[row * 512 + h * 64 + ni * 16 + l16] = __float2bfloat16(acc_o[ni][r] * linv[r]);
    }
}

// ---------------- fused dual LN over two split-K partials ----------------
__global__ __launch_bounds__(256) void k_ln2(
    const float* x0, const float* g0, const float* b0, float* yf0, bf16* yb0,
    const float* x1, const float* g1, const float* b1, float* yf1, bf16* yb1,
    const float* __restrict__ P, long pstr)
{
  int sel = blockIdx.x >> 12;
  long row = blockIdx.x & 4095;
  const float* x = sel ? x1 : x0;
  const float* g = sel ? g1 : g0;
  const float* bb = sel ? b1 : b0;
  float* yf = sel ? yf1 : yf0;
  bf16* yb = sel ? yb1 : yb0;
  int t = threadIdx.x;
  const float* xr = x + row * D_;
  const float* ra = P + (sel ? 2 : 0) * pstr + row * D_;
  const float* rb = ra + pstr;
  float v0 = xr[t] + ra[t] + rb[t];
  float v1 = xr[t + 256] + ra[t + 256] + rb[t + 256];
  float s = v0 + v1;
  float ss = v0 * v0 + v1 * v1;
#pragma unroll
  for (int o = 32; o > 0; o >>= 1) {
    s += __shfl_down(s, o, 64);
    ss += __shfl_down(ss, o, 64);
  }
  __shared__ float rs[4];
  __shared__ float rss[4];
  int lane = t & 63, wid = t >> 6;
  if (lane == 0) { rs[wid] = s; rss[wid] = ss; }
  __syncthreads();
  s = rs[0] + rs[1] + rs[2] + rs[3];
  ss = rss[0] + rss[1] + rss[2] + rss[3];
  float mean = s * (1.0f / D_);
  float var = ss * (1.0f / D_) - mean * mean;
  float rstd = rsqrtf(var + 1e-5f);
  float o0 = (v0 - mean) * rstd * g[t]       + bb[t];
  float o1 = (v1 - mean) * rstd * g[t + 256] + bb[t + 256];
  if (yf) { float* yr = yf + row * D_; yr[t] = o0; yr[t + 256] = o1; }
  if (yb) { bf16* yr = yb + row * D_; yr[t] = __float2bfloat16(o0); yr[t + 256] = __float2bfloat16(o1); }
}

// ---------------- sum two fp32 partials -> bf16 ----------------
__global__ __launch_bounds__(256) void k_sum2bf(const float* __restrict__ a,
                                                const float* __restrict__ b,
                                                bf16* __restrict__ o)
{
  int i = (blockIdx.x * 256 + threadIdx.x) * 4;
  float4 va = *(const float4*)(a + i);
  float4 vb = *(const float4*)(b + i);
  bf16 ov[4] = { __float2bfloat16(va.x + vb.x), __float2bfloat16(va.y + vb.y),
                 __float2bfloat16(va.z + vb.z), __float2bfloat16(va.w + vb.w) };
  *(short4v*)&o[i] = *(const short4v*)ov;
}

// ---------------- wave-per-row cross-masked softmax (final pooling) ----------------
__global__ __launch_bounds__(256) void k_softmax_x(float* __restrict__ S,
                                                   const int* __restrict__ vm,
                                                   const int* __restrict__ qm)
{
  int wrow = blockIdx.x * 4 + (threadIdx.x >> 6);
  int lane = threadIdx.x & 63;
  int b = wrow >> 9, i = wrow & 511;
  bool rowpad = (vm[(b << 9) + i] == 0);
  float* p = S + (long)wrow * 512;
  const int* qb = qm + (b << 9);
  int j0 = lane * 8;
  float4 a0 = *(const float4*)(p + j0);
  float4 a1 = *(const float4*)(p + j0 + 4);
  int4 m0 = *(const int4*)(qb + j0);
  int4 m1 = *(const int4*)(qb + j0 + 4);
  float v[8];
  v[0] = (rowpad || !m0.x) ? -1e9f : a0.x; v[1] = (rowpad || !m0.y) ? -1e9f : a0.y;
  v[2] = (rowpad || !m0.z) ? -1e9f : a0.z; v[3] = (rowpad || !m0.w) ? -1e9f : a0.w;
  v[4] = (rowpad || !m1.x) ? -1e9f : a1.x; v[5] = (rowpad || !m1.y) ? -1e9f : a1.y;
  v[6] = (rowpad || !m1.z) ? -1e9f : a1.z; v[7] = (rowpad || !m1.w) ? -1e9f : a1.w;
  float mx = v[0];
#pragma unroll
  for (int u = 1; u < 8; ++u) mx = fmaxf(mx, v[u]);
#pragma unroll
  for (int o = 1; o < 64; o <<= 1) mx = fmaxf(mx, __shfl_xor(mx, o, 64));
  float e[8], sum = 0.f;
#pragma unroll
  for (int u = 0; u < 8; ++u) { e[u] = __expf(v[u] - mx); sum += e[u]; }
#pragma unroll
  for (int o = 1; o < 64; o <<= 1) sum += __shfl_xor(sum, o, 64);
  float inv = 1.0f / sum;
  bf16 ob[8];
#pragma unroll
  for (int u = 0; u < 8; ++u) ob[u] = __float2bfloat16(e[u] * inv);
  bf16* pb = (bf16*)p;
  *(short8*)&pb[j0] = *(const short8*)ob;
}

// ---------------- final prep: Vw = bf16(V*w); Qt = bf16(Q^T) per batch ----------------
__global__ __launch_bounds__(256) void k_vwqt(const float* __restrict__ V,
                                              const float* __restrict__ Q,
                                              const float* __restrict__ w,
                                              bf16* __restrict__ Vw, bf16* __restrict__ Qt)
{
  __shared__ float Ls[32][33];
  int bx = blockIdx.x, t = threadIdx.x;
  if (bx < 2048) {
    int i = bx * 1024 + t * 4;
    float4 v = *(const float4*)(V + i);
    int k = i & 511;
    bf16 o[4] = { __float2bfloat16(v.x * w[k]),     __float2bfloat16(v.y * w[k + 1]),
                  __float2bfloat16(v.z * w[k + 2]), __float2bfloat16(v.w * w[k + 3]) };
    *(short4v*)&Vw[i] = *(const short4v*)o;
  } else {
    int q = bx - 2048; int b = q >> 8; int tq = q & 255;
    int tr = tq >> 4, tc = tq & 15;
    const float* Qb = Q + (long)b * 262144;
    bf16* Qtb = Qt + (long)b * 262144;
#pragma unroll
    for (int p = 0; p < 4; ++p) {
      int idx = t + p * 256; int lr = idx >> 5, lc = idx & 31;
      Ls[lr][lc] = Qb[(long)(tr * 32 + lr) * 512 + tc * 32 + lc];
    }
    __syncthreads();
#pragma unroll
    for (int p = 0; p < 4; ++p) {
      int idx = t + p * 256; int lr = idx >> 5, lc = idx & 31;
      Qtb[(long)(tc * 32 + lr) * 512 + tr * 32 + lc] = __float2bfloat16(Ls[lc][lr]);
    }
  }
}

// ---------------- out[b,k] = (1/512) * sum_i V[b,i,k] * T[b,i,k] ----------------
__global__ __launch_bounds__(256) void k_final_out(
    const float* __restrict__ V, const float* __restrict__ QT, float* __restrict__ out)
{
  int b = blockIdx.x >> 1;
  int k = ((blockIdx.x & 1) << 8) + threadIdx.x;
  const float* Vb = V + (long)b * N_ * D_ + k;
  const float* Tb = QT + (long)b * N_ * D_ + k;
  float acc = 0.0f;
  for (int i = 0; i < N_; ++i) acc += Vb[(long)i * D_] * Tb[(long)i * D_];
  out[b * D_ + k] = acc * (1.0f / 512.0f);
}

extern "C" void kernel_launch(void* const* d_in, const int* in_sizes, int n_in,
                              void* d_out, int out_size, void* d_ws, size_t ws_size,
                              hipStream_t stream)
{
  const float* in_v   = (const float*)d_in[0];
  const float* in_q   = (const float*)d_in[1];
  const int*   v_mask = (const int*)  d_in[2];
  const int*   q_mask = (const int*)  d_in[3];
  const float* aw  = (const float*)d_in[4];
  const float* ab  = (const float*)d_in[5];
  const float* awo = (const float*)d_in[6];
  const float* abo = (const float*)d_in[7];
  const float* lg  = (const float*)d_in[8];
  const float* lb  = (const float*)d_in[9];
  const float* fw1 = (const float*)d_in[10];
  const float* fb1 = (const float*)d_in[11];
  const float* fw2 = (const float*)d_in[12];
  const float* fb2 = (const float*)d_in[13];
  const float* atw = (const float*)d_in[14];
  const float* atb = (const float*)d_in[15];
  float* out = (float*)d_out;
  (void)atb;  // softmax is shift-invariant

  const int SZ = B_ * N_ * D_;
  char* wsb = (char*)d_ws;
  const long MB = 1024L * 1024;
  float* Vcur   = (float*)(wsb + 0 * MB);
  float* Qcur   = (float*)(wsb + 8 * MB);
  float* P0     = (float*)(wsb + 16 * MB);
  const long PSZ = 2097152;               // floats per partial (8 MB)
  bf16*  WT     = (bf16*) (wsb + 48 * MB);
  bf16*  Vcur_b = (bf16*) (wsb + 64 * MB);
  bf16*  Qcur_b = (bf16*) (wsb + 68 * MB);
  bf16*  VA_b   = (bf16*) (wsb + 72 * MB);
  bf16*  QA_b   = (bf16*) (wsb + 76 * MB);
  bf16*  VQ_b   = (bf16*) (wsb + 80 * MB);
  bf16*  QKV0   = (bf16*) (wsb + 84 * MB);
  bf16*  Hid    = (bf16*) (wsb + 108 * MB);
  float* Sf     = P0;
  bf16*  Vw_b   = (bf16*) (wsb + 24 * MB);
  bf16*  Qt_b   = (bf16*) (wsb + 28 * MB);
  float* Tfin   = (float*)(wsb + 32 * MB);

  const long ZBIG = 1000000;

  k_prep2<<<16384, 256, 0, stream>>>(in_v, Vcur, Vcur_b, in_q, Qcur, Qcur_b, SZ);

  for (int l = 0; l < L_; ++l) {
    const float* lgl = lg + (long)l * 6 * D_;
    const float* lbl = lb + (long)l * 6 * D_;
    k_wt<<<8192, 256, 0, stream>>>(aw + (long)l * 12 * 262144,
                                   awo + (long)l * 4 * 262144,
                                   fw1 + (long)l * 2 * 1048576,
                                   fw2 + (long)l * 2 * 1048576, WT);
    // ---- self-attention (2 streams: s0=v, s1=q) ----
    k_mfma<128><<<dim3(12, 32, 2), 256, 0, stream>>>(
        Vcur_b, Vcur_b, 2097152, 0, 0, 512,
        WT, 1048576, 0, 0, 512,
        ab + (long)l * 4 * 1536, 1536, 1.f, 0,
        nullptr, 0, 0, 0, 0, QKV0, 6291456, 0, 0, 0,
        512, 1, 1, 1, 1, 0);
    k_flash<<<dim3(8, 64, 2), 256, 0, stream>>>(QKV0, 6291456, v_mask, q_mask, 0.125f);
    k_mfma<128><<<dim3(4, 32, 4), 256, 0, stream>>>(      // out-proj, splitK=2 x 2 streams
        QKV0, QKV0, 6291456, 0, 0, 512,
        WT + 3 * 262144, 1048576, 0, 0, 512,
        abo + (long)l * 4 * 512, 512, 1.f, 0,
        P0, 2 * PSZ, 0, 0, 512, nullptr, 0, 0, 0, 0,
        256, 1, 1, 0, 2, PSZ);
    k_ln2<<<8192, 256, 0, stream>>>(Vcur, lgl + 0 * D_, lbl + 0 * D_, nullptr, VA_b,
                                    Qcur, lgl + 1 * D_, lbl + 1 * D_, nullptr, QA_b,
                                    P0, PSZ);
    // ---- cross attention vq: xq=VA, xkv=QA ----
    k_mfma<128><<<dim3(12, 32, 1), 256, 0, stream>>>(
        VA_b, QA_b, 0, 0, 0, 512,
        WT + 2 * 1048576, 0, 0, 0, 512,
        ab + (long)(l * 4 + 2) * 1536, 0, 1.f, 0,
        nullptr, 0, 0, 0, 0, QKV0, 0, 0, 0, 0,
        512, 1, 1, 1, 1, 0);
    k_flash<<<dim3(8, 64, 1), 256, 0, stream>>>(QKV0, 0, q_mask, q_mask, 0.125f);
    k_mfma<64><<<dim3(8, 32, 2), 256, 0, stream>>>(       // out-proj vq -> P0,P1
        QKV0, QKV0, 0, 0, 0, 512,
        WT + (2 * 4 + 3) * 262144, 0, 0, 0, 512,
        abo + (long)(l * 4 + 2) * 512, 0, 1.f, 0,
        P0, 0, 0, 0, 512, nullptr, 0, 0, 0, 0,
        256, 1, 1, 0, 2, PSZ);
    k_sum2bf<<<2048, 256, 0, stream>>>(P0, P0 + PSZ, VQ_b);
    // ---- cross attention qv: xq=QA, xkv=VQ ----
    k_mfma<128><<<dim3(12, 32, 1), 256, 0, stream>>>(
        QA_b, VQ_b, 0, 0, 0, 512,
        WT + 3 * 1048576, 0, 0, 0, 512,
        ab + (long)(l * 4 + 3) * 1536, 0, 1.f, 0,
        nullptr, 0, 0, 0, 0, QKV0, 0, 0, 0, 0,
        512, 1, 1, 1, 1, 0);
    k_flash<<<dim3(8, 64, 1), 256, 0, stream>>>(QKV0, 0, v_mask, v_mask, 0.125f);
    k_mfma<64><<<dim3(8, 32, 2), 256, 0, stream>>>(       // out-proj qv -> P2,P3
        QKV0, QKV0, 0, 0, 0, 512,
        WT + (3 * 4 + 3) * 262144, 0, 0, 0, 512,
        abo + (long)(l * 4 + 3) * 512, 0, 1.f, 0,
        P0 + 2 * PSZ, 0, 0, 0, 512, nullptr, 0, 0, 0, 0,
        256, 1, 1, 0, 2, PSZ);
    k_ln2<<<8192, 256, 0, stream>>>(Vcur, lgl + 2 * D_, lbl + 2 * D_, Vcur, Vcur_b,
                                    Qcur, lgl + 3 * D_, lbl + 3 * D_, Qcur, Qcur_b,
                                    P0, PSZ);
    // ---- FFN (2 streams) ----
    k_mfma<128><<<dim3(16, 32, 2), 256, 0, stream>>>(
        Vcur_b, Vcur_b, 2097152, 0, 0, 512,
        WT + 4194304, 1048576, 0, 0, 512,
        fb1 + (long)l * 2 * 2048, 2048, 1.f, 1,
        nullptr, 0, 0, 0, 0, Hid, 8388608, 0, 0, 2048,
        512, 1, 1, 0, 1, 0);
    k_mfma<128><<<dim3(4, 32, 4), 256, 0, stream>>>(      // fc2 splitK=2 x 2 streams
        Hid, Hid, 8388608, 0, 0, 2048,
        WT + 6291456, 1048576, 0, 0, 2048,
        fb2 + (long)l * 2 * 512, 512, 1.f, 0,
        P0, 2 * PSZ, 0, 0, 512, nullptr, 0, 0, 0, 0,
        1024, 1, 1, 0, 2, PSZ);
    k_ln2<<<8192, 256, 0, stream>>>(Vcur, lgl + 4 * D_, lbl + 4 * D_, Vcur, Vcur_b,
                                    Qcur, lgl + 5 * D_, lbl + 5 * D_, Qcur, Qcur_b,
                                    P0, PSZ);
  }

  // ---- final bilinear attention pooling ----
  k_vwqt<<<4096, 256, 0, stream>>>(Vcur, Qcur, atw, Vw_b, Qt_b);
  k_mfma<128><<<dim3(4, 4, 8), 256, 0, stream>>>(          // scores = (V*w) @ Q^T -> Sf(=P0)
      Vw_b, Vw_b, 0, 262144, 0, 512, Qcur_b, 0, 262144, 0, 512,
      nullptr, 0, 1.f, 0,
      Sf, 0, 262144, 0, 512, nullptr, 0, 0, 0, 0,
      512, 1, ZBIG, 0, 1, 0);
  k_softmax_x<<<1024, 256, 0, stream>>>(Sf, v_mask, q_mask);
  k_mfma<128><<<dim3(4, 4, 8), 256, 0, stream>>>(          // Tfin = P @ Q
      (const bf16*)Sf, (const bf16*)Sf, 0, 524288, 0, 1024, Qt_b, 0, 262144, 0, 512,
      nullptr, 0, 1.f, 0,
      Tfin, 0, 262144, 0, 512, nullptr, 0, 0, 0, 0,
      512, 1, ZBIG, 0, 1, 0);
  k_final_out<<<16, 256, 0, stream>>>(Vcur, Tfin, out);

  (void)in_sizes; (void)n_in; (void)out_size; (void)ws_size;
}